// Round 1
// baseline (757.008 us; speedup 1.0000x reference)
//
#include <hip/hip_runtime.h>

#define NN 50000
#define EE 1600000

// ---------------- graph build ----------------
__global__ void k_zero(int* __restrict__ p, int n) {
    int i = blockIdx.x * blockDim.x + threadIdx.x;
    if (i < n) p[i] = 0;
}

__global__ void k_hist(const int* __restrict__ dst, int* __restrict__ cnt, int e) {
    int i = blockIdx.x * blockDim.x + threadIdx.x;
    if (i < e) atomicAdd(&cnt[dst[i]], 1);
}

__global__ void k_dinv(const int* __restrict__ cnt, float* __restrict__ dinv, int n) {
    int i = blockIdx.x * blockDim.x + threadIdx.x;
    if (i < n) dinv[i] = rsqrtf((float)(cnt[i] + 1));  // deg includes self-loop, >=1
}

__global__ void k_scan1(const int* __restrict__ cnt, int* __restrict__ rowptr,
                        int* __restrict__ part, int n) {
    __shared__ int sh[256];
    int tid = threadIdx.x;
    int i = blockIdx.x * 256 + tid;
    int v = (i < n) ? cnt[i] : 0;
    int x = v;
    sh[tid] = x;
    __syncthreads();
    for (int off = 1; off < 256; off <<= 1) {
        int t = (tid >= off) ? sh[tid - off] : 0;
        __syncthreads();
        if (tid >= off) { x += t; sh[tid] = x; }
        __syncthreads();
    }
    if (i < n) rowptr[i] = x - v;            // block-local exclusive
    if (tid == 255) part[blockIdx.x] = x;    // block sum
}

__global__ void k_scan2(int* __restrict__ part, int nb) {
    __shared__ int sh[256];
    int tid = threadIdx.x;
    int v = (tid < nb) ? part[tid] : 0;
    int x = v;
    sh[tid] = x;
    __syncthreads();
    for (int off = 1; off < 256; off <<= 1) {
        int t = (tid >= off) ? sh[tid - off] : 0;
        __syncthreads();
        if (tid >= off) { x += t; sh[tid] = x; }
        __syncthreads();
    }
    if (tid < nb) part[tid] = x - v;         // exclusive block offsets
}

__global__ void k_scan3(int* __restrict__ rowptr, const int* __restrict__ part,
                        int* __restrict__ cursor, int n, int e) {
    int i = blockIdx.x * blockDim.x + threadIdx.x;
    if (i < n) {
        int r = rowptr[i] + part[i >> 8];
        rowptr[i] = r;
        cursor[i] = r;
    }
    if (i == 0) rowptr[n] = e;
}

__global__ void k_scatter(const int* __restrict__ src, const int* __restrict__ dst,
                          const float* __restrict__ dinv, int* __restrict__ cursor,
                          int* __restrict__ es, float* __restrict__ ew, int e) {
    int i = blockIdx.x * blockDim.x + threadIdx.x;
    if (i < e) {
        int s = src[i], d = dst[i];
        float w = dinv[s] * dinv[d];
        int p = atomicAdd(&cursor[d], 1);   // order within bucket irrelevant
        es[p] = s;
        ew[p] = w;
    }
}

// ---------------- fp32 tiled GEMM: C[M,Nc] = A[M,K] @ B[K,Nc] ----------------
#define BM 128
#define BN 128
#define BK 16

__global__ __launch_bounds__(256) void k_gemm(const float* __restrict__ A,
                                              const float* __restrict__ B,
                                              float* __restrict__ C,
                                              int M, int Nc, int K) {
    __shared__ float As[BK][BM];   // transposed A tile
    __shared__ float Bs[BK][BN];

    const int tid = threadIdx.x;
    const int tx = tid & 15;   // 16 col groups of 8
    const int ty = tid >> 4;   // 16 row groups of 8
    const int rowBase = blockIdx.x * BM;
    const int colBase = blockIdx.y * BN;

    // A staging: thread loads A[rowBase + tid/2][k0 + (tid&1)*8 .. +7]
    const int a_row = tid >> 1;
    const int a_k = (tid & 1) * 8;
    const bool a_valid = (rowBase + a_row) < M;
    const float* Aptr = A + (size_t)(rowBase + a_row) * K + a_k;

    // B staging: thread loads B[k0 + tid/16][colBase + (tid&15)*8 .. +7]
    const int b_k = tid >> 4;
    const int b_c = (tid & 15) * 8;
    const float* Bptr = B + (size_t)b_k * Nc + colBase + b_c;

    float acc[8][8];
#pragma unroll
    for (int i = 0; i < 8; i++)
#pragma unroll
        for (int j = 0; j < 8; j++) acc[i][j] = 0.f;

    for (int kt = 0; kt < K; kt += BK) {
        float4 a0 = make_float4(0.f, 0.f, 0.f, 0.f), a1 = a0;
        if (a_valid) {
            a0 = *(const float4*)(Aptr + kt);
            a1 = *(const float4*)(Aptr + kt + 4);
        }
        float4 b0 = *(const float4*)(Bptr + (size_t)kt * Nc);
        float4 b1 = *(const float4*)(Bptr + (size_t)kt * Nc + 4);
        __syncthreads();
        As[a_k + 0][a_row] = a0.x; As[a_k + 1][a_row] = a0.y;
        As[a_k + 2][a_row] = a0.z; As[a_k + 3][a_row] = a0.w;
        As[a_k + 4][a_row] = a1.x; As[a_k + 5][a_row] = a1.y;
        As[a_k + 6][a_row] = a1.z; As[a_k + 7][a_row] = a1.w;
        *(float4*)&Bs[b_k][b_c] = b0;
        *(float4*)&Bs[b_k][b_c + 4] = b1;
        __syncthreads();
#pragma unroll
        for (int k = 0; k < BK; k++) {
            float a[8], b[8];
            *(float4*)&a[0] = *(const float4*)&As[k][ty * 8];
            *(float4*)&a[4] = *(const float4*)&As[k][ty * 8 + 4];
            *(float4*)&b[0] = *(const float4*)&Bs[k][tx * 8];
            *(float4*)&b[4] = *(const float4*)&Bs[k][tx * 8 + 4];
#pragma unroll
            for (int i = 0; i < 8; i++)
#pragma unroll
                for (int j = 0; j < 8; j++) acc[i][j] += a[i] * b[j];
        }
    }

#pragma unroll
    for (int i = 0; i < 8; i++) {
        int r = rowBase + ty * 8 + i;
        if (r < M) {
            float4 c0 = make_float4(acc[i][0], acc[i][1], acc[i][2], acc[i][3]);
            float4 c1 = make_float4(acc[i][4], acc[i][5], acc[i][6], acc[i][7]);
            *(float4*)(C + (size_t)r * Nc + colBase + tx * 8) = c0;
            *(float4*)(C + (size_t)r * Nc + colBase + tx * 8 + 4) = c1;
        }
    }
}

// ---------------- propagation: one wave per dst node ----------------
// Y[i,:] = sum_{e: dst=i} w_e * X[src_e,:] + dinv[i]^2 * X[i,:]  (+bias, relu)
template <bool RELU>
__global__ void k_prop256(const float* __restrict__ Xin, const int* __restrict__ rowptr,
                          const int* __restrict__ es, const float* __restrict__ ew,
                          const float* __restrict__ dinv, const float* __restrict__ bias,
                          float* __restrict__ Yout, int n) {
    const int wid = (int)((blockIdx.x * blockDim.x + threadIdx.x) >> 6);
    const int lane = threadIdx.x & 63;
    if (wid >= n) return;
    const float di = dinv[wid];
    const float wself = di * di;
    const float4 v = *(const float4*)(Xin + (size_t)wid * 256 + lane * 4);
    float4 acc = make_float4(v.x * wself, v.y * wself, v.z * wself, v.w * wself);
    const int beg = rowptr[wid];
    const int end = rowptr[wid + 1];
    int j = beg;
    for (; j + 1 < end; j += 2) {
        const int s0 = es[j], s1 = es[j + 1];
        const float w0 = ew[j], w1 = ew[j + 1];
        const float4 u0 = *(const float4*)(Xin + (size_t)s0 * 256 + lane * 4);
        const float4 u1 = *(const float4*)(Xin + (size_t)s1 * 256 + lane * 4);
        acc.x += u0.x * w0 + u1.x * w1;
        acc.y += u0.y * w0 + u1.y * w1;
        acc.z += u0.z * w0 + u1.z * w1;
        acc.w += u0.w * w0 + u1.w * w1;
    }
    if (j < end) {
        const int s0 = es[j];
        const float w0 = ew[j];
        const float4 u0 = *(const float4*)(Xin + (size_t)s0 * 256 + lane * 4);
        acc.x += u0.x * w0; acc.y += u0.y * w0; acc.z += u0.z * w0; acc.w += u0.w * w0;
    }
    const float4 b = *(const float4*)(bias + lane * 4);
    acc.x += b.x; acc.y += b.y; acc.z += b.z; acc.w += b.w;
    if (RELU) {
        acc.x = fmaxf(acc.x, 0.f); acc.y = fmaxf(acc.y, 0.f);
        acc.z = fmaxf(acc.z, 0.f); acc.w = fmaxf(acc.w, 0.f);
    }
    *(float4*)(Yout + (size_t)wid * 256 + lane * 4) = acc;
}

template <bool RELU>
__global__ void k_prop128(const float* __restrict__ Xin, const int* __restrict__ rowptr,
                          const int* __restrict__ es, const float* __restrict__ ew,
                          const float* __restrict__ dinv, const float* __restrict__ bias,
                          float* __restrict__ Yout, int n) {
    const int wid = (int)((blockIdx.x * blockDim.x + threadIdx.x) >> 6);
    const int lane = threadIdx.x & 63;
    if (wid >= n) return;
    const float di = dinv[wid];
    const float wself = di * di;
    const float2 v = *(const float2*)(Xin + (size_t)wid * 128 + lane * 2);
    float2 acc = make_float2(v.x * wself, v.y * wself);
    const int beg = rowptr[wid];
    const int end = rowptr[wid + 1];
    int j = beg;
    for (; j + 1 < end; j += 2) {
        const int s0 = es[j], s1 = es[j + 1];
        const float w0 = ew[j], w1 = ew[j + 1];
        const float2 u0 = *(const float2*)(Xin + (size_t)s0 * 128 + lane * 2);
        const float2 u1 = *(const float2*)(Xin + (size_t)s1 * 128 + lane * 2);
        acc.x += u0.x * w0 + u1.x * w1;
        acc.y += u0.y * w0 + u1.y * w1;
    }
    if (j < end) {
        const int s0 = es[j];
        const float w0 = ew[j];
        const float2 u0 = *(const float2*)(Xin + (size_t)s0 * 128 + lane * 2);
        acc.x += u0.x * w0; acc.y += u0.y * w0;
    }
    const float2 b = *(const float2*)(bias + lane * 2);
    acc.x += b.x; acc.y += b.y;
    if (RELU) { acc.x = fmaxf(acc.x, 0.f); acc.y = fmaxf(acc.y, 0.f); }
    *(float2*)(Yout + (size_t)wid * 128 + lane * 2) = acc;
}

extern "C" void kernel_launch(void* const* d_in, const int* in_sizes, int n_in,
                              void* d_out, int out_size, void* d_ws, size_t ws_size,
                              hipStream_t stream) {
    const float* x  = (const float*)d_in[0];
    const int*   ei = (const int*)d_in[1];
    const float* W1 = (const float*)d_in[2];
    const float* b1 = (const float*)d_in[3];
    const float* W2 = (const float*)d_in[4];
    const float* b2 = (const float*)d_in[5];
    float* out = (float*)d_out;

    const int n = in_sizes[0] / 256;  // 50000
    const int e = in_sizes[1] / 2;    // 1600000
    const int* src = ei;
    const int* dst = ei + e;

    // workspace carve-out (512B aligned); total ~110.5 MiB
    char* wsp = (char*)d_ws;
    size_t off = 0;
    auto alloc = [&](size_t bytes) -> char* {
        char* p = wsp + off;
        off += (bytes + 511) & ~(size_t)511;
        return p;
    };
    int*   cnt    = (int*)alloc(sizeof(int) * n);       // histogram, then cursor
    float* dinv   = (float*)alloc(sizeof(float) * n);
    int*   rowptr = (int*)alloc(sizeof(int) * (n + 1));
    int*   part   = (int*)alloc(sizeof(int) * 256);
    int*   es     = (int*)alloc(sizeof(int) * e);       // CSR src indices
    float* ewt    = (float*)alloc(sizeof(float) * e);   // CSR edge weights
    float* bufA   = (float*)alloc(sizeof(float) * (size_t)n * 256);  // XW1, then HW2
    float* bufB   = (float*)alloc(sizeof(float) * (size_t)n * 256);  // H

    const int nb_n = (n + 255) / 256;  // 196
    const int nb_e = (e + 255) / 256;

    // ---- CSR build ----
    k_zero<<<nb_n, 256, 0, stream>>>(cnt, n);
    k_hist<<<nb_e, 256, 0, stream>>>(dst, cnt, e);
    k_dinv<<<nb_n, 256, 0, stream>>>(cnt, dinv, n);
    k_scan1<<<nb_n, 256, 0, stream>>>(cnt, rowptr, part, n);
    k_scan2<<<1, 256, 0, stream>>>(part, nb_n);
    k_scan3<<<nb_n, 256, 0, stream>>>(rowptr, part, cnt, n, e);
    k_scatter<<<nb_e, 256, 0, stream>>>(src, dst, dinv, cnt, es, ewt, e);

    // ---- layer 1: bufA = x @ W1; bufB = relu(prop(bufA) + b1) ----
    dim3 g1((n + BM - 1) / BM, 256 / BN);
    k_gemm<<<g1, 256, 0, stream>>>(x, W1, bufA, n, 256, 256);
    k_prop256<true><<<(n + 3) / 4, 256, 0, stream>>>(bufA, rowptr, es, ewt, dinv, b1, bufB, n);

    // ---- layer 2: bufA = bufB @ W2; out = prop(bufA) + b2 ----
    dim3 g2((n + BM - 1) / BM, 128 / BN);
    k_gemm<<<g2, 256, 0, stream>>>(bufB, W2, bufA, n, 128, 256);
    k_prop128<false><<<(n + 3) / 4, 256, 0, stream>>>(bufA, rowptr, es, ewt, dinv, b2, out, n);
}

// Round 3
// 513.366 us; speedup vs baseline: 1.4746x; 1.4746x over previous
//
#include <hip/hip_runtime.h>

typedef short s16x8 __attribute__((ext_vector_type(8)));
typedef float f32x4 __attribute__((ext_vector_type(4)));

// ---------- bf16 helpers (bit-level, RNE) ----------
__device__ __forceinline__ unsigned int brne(float f) {
    unsigned int u = __float_as_uint(f);
    return (u + 0x7FFFu + ((u >> 16) & 1u)) >> 16;   // bf16 bits in low 16
}
__device__ __forceinline__ float blo(unsigned int u) { return __uint_as_float(u << 16); }
__device__ __forceinline__ float bhi(unsigned int u) { return __uint_as_float(u & 0xFFFF0000u); }

// ---------------- graph build ----------------
__global__ void k_zero(int* __restrict__ p, int n) {
    int i = blockIdx.x * blockDim.x + threadIdx.x;
    if (i < n) p[i] = 0;
}

__global__ void k_hist(const int* __restrict__ dst, int* __restrict__ cnt, int e) {
    int i = blockIdx.x * blockDim.x + threadIdx.x;
    if (i < e) atomicAdd(&cnt[dst[i]], 1);
}

__global__ void k_dinv(const int* __restrict__ cnt, float* __restrict__ dinv, int n) {
    int i = blockIdx.x * blockDim.x + threadIdx.x;
    if (i < n) dinv[i] = rsqrtf((float)(cnt[i] + 1));  // deg includes self-loop
}

__global__ void k_scan1(const int* __restrict__ cnt, int* __restrict__ rowptr,
                        int* __restrict__ part, int n) {
    __shared__ int sh[256];
    int tid = threadIdx.x;
    int i = blockIdx.x * 256 + tid;
    int v = (i < n) ? cnt[i] : 0;
    int x = v;
    sh[tid] = x;
    __syncthreads();
    for (int off = 1; off < 256; off <<= 1) {
        int t = (tid >= off) ? sh[tid - off] : 0;
        __syncthreads();
        if (tid >= off) { x += t; sh[tid] = x; }
        __syncthreads();
    }
    if (i < n) rowptr[i] = x - v;
    if (tid == 255) part[blockIdx.x] = x;
}

__global__ void k_scan2(int* __restrict__ part, int nb) {
    __shared__ int sh[256];
    int tid = threadIdx.x;
    int v = (tid < nb) ? part[tid] : 0;
    int x = v;
    sh[tid] = x;
    __syncthreads();
    for (int off = 1; off < 256; off <<= 1) {
        int t = (tid >= off) ? sh[tid - off] : 0;
        __syncthreads();
        if (tid >= off) { x += t; sh[tid] = x; }
        __syncthreads();
    }
    if (tid < nb) part[tid] = x - v;
}

__global__ void k_scan3(int* __restrict__ rowptr, const int* __restrict__ part,
                        int* __restrict__ cursor, int n, int e) {
    int i = blockIdx.x * blockDim.x + threadIdx.x;
    if (i < n) {
        int r = rowptr[i] + part[i >> 8];
        rowptr[i] = r;
        cursor[i] = r;
    }
    if (i == 0) rowptr[n] = e;
}

__global__ void k_scatter(const int* __restrict__ src, const int* __restrict__ dst,
                          const float* __restrict__ dinv, int* __restrict__ cursor,
                          int* __restrict__ es, float* __restrict__ ew, int e) {
    int i = blockIdx.x * blockDim.x + threadIdx.x;
    if (i < e) {
        int s = src[i], d = dst[i];
        float w = dinv[s] * dinv[d];
        int p = atomicAdd(&cursor[d], 1);
        es[p] = s;
        ew[p] = w;
    }
}

// ---------------- dtype prep ----------------
// x fp32 -> bf16, 4 elems/thread
__global__ void k_cast_x(const float* __restrict__ x, unsigned int* __restrict__ xb2,
                         int total4) {
    int i = blockIdx.x * blockDim.x + threadIdx.x;
    if (i >= total4) return;
    float4 v = ((const float4*)x)[i];
    uint2 p;
    p.x = brne(v.x) | (brne(v.y) << 16);
    p.y = brne(v.z) | (brne(v.w) << 16);
    ((uint2*)xb2)[i] = p;
}

// W[K][N] fp32 -> Wt[N][K] bf16 (K=256, N = 1<<nshift)
__global__ void k_tW(const float* __restrict__ W, unsigned short* __restrict__ Wt,
                     int total, int nshift) {
    int t = blockIdx.x * blockDim.x + threadIdx.x;
    if (t >= total) return;
    int k = t >> nshift;
    int nn = t & ((1 << nshift) - 1);
    Wt[(size_t)nn * 256 + k] = (unsigned short)brne(W[t]);
}

// ---------------- bf16 MFMA GEMM: C[M,Nc] = A[M,256] @ Bt[Nc,256]^T ----------------
// 128x128 block tile, 4 waves (2x2 of 64x64), BK=32, K=256 fixed.
__global__ __launch_bounds__(256) void k_gemm_bf16(const unsigned short* __restrict__ A,
                                                   const unsigned short* __restrict__ Bt,
                                                   unsigned short* __restrict__ C,
                                                   int M, int Nc) {
    __shared__ unsigned short As[128 * 32];
    __shared__ unsigned short Bs[128 * 32];

    const int tid = threadIdx.x;
    const int wave = tid >> 6, lane = tid & 63;
    const int wm = (wave >> 1) * 64, wn = (wave & 1) * 64;
    const int l15 = lane & 15, quad = lane >> 4;
    const int mBase = blockIdx.x * 128, nBase = blockIdx.y * 128;

    f32x4 acc[4][4];
#pragma unroll
    for (int i = 0; i < 4; i++)
#pragma unroll
        for (int j = 0; j < 4; j++) acc[i][j] = (f32x4){0.f, 0.f, 0.f, 0.f};

    // staging: chunk c covers row c>>2, 16B piece c&3 (row = 32 bf16 = 64B per K-tile)
    const int c0 = tid, c1 = 256 + tid;
    const int r0 = c0 >> 2, kc0 = c0 & 3;
    const int r1 = c1 >> 2, kc1 = c1 & 3;
    int am0 = mBase + r0; if (am0 >= M) am0 = M - 1;
    int am1 = mBase + r1; if (am1 >= M) am1 = M - 1;
    // full row = 256 bf16 = 32 uint4
    const uint4* Ap0 = (const uint4*)A + (size_t)am0 * 32 + kc0;
    const uint4* Ap1 = (const uint4*)A + (size_t)am1 * 32 + kc1;
    const uint4* Bp0 = (const uint4*)Bt + (size_t)(nBase + r0) * 32 + kc0;
    const uint4* Bp1 = (const uint4*)Bt + (size_t)(nBase + r1) * 32 + kc1;

    for (int kt = 0; kt < 8; ++kt) {
        uint4 a0 = Ap0[kt * 4];
        uint4 a1 = Ap1[kt * 4];
        uint4 b0 = Bp0[kt * 4];
        uint4 b1 = Bp1[kt * 4];
        __syncthreads();
        *(uint4*)&As[c0 * 8] = a0;
        *(uint4*)&As[c1 * 8] = a1;
        *(uint4*)&Bs[c0 * 8] = b0;
        *(uint4*)&Bs[c1 * 8] = b1;
        __syncthreads();

        s16x8 af[4], bf[4];
#pragma unroll
        for (int i = 0; i < 4; i++)
            af[i] = *(const s16x8*)&As[(wm + i * 16 + l15) * 32 + quad * 8];
#pragma unroll
        for (int j = 0; j < 4; j++)
            bf[j] = *(const s16x8*)&Bs[(wn + j * 16 + l15) * 32 + quad * 8];
#pragma unroll
        for (int i = 0; i < 4; i++)
#pragma unroll
            for (int j = 0; j < 4; j++)
                acc[i][j] = __builtin_amdgcn_mfma_f32_16x16x32_bf16(af[i], bf[j], acc[i][j], 0, 0, 0);
    }

#pragma unroll
    for (int i = 0; i < 4; i++) {
        const int rowb = mBase + wm + i * 16 + quad * 4;
#pragma unroll
        for (int r = 0; r < 4; r++) {
            const int row = rowb + r;
            if (row < M) {
#pragma unroll
                for (int j = 0; j < 4; j++) {
                    const int col = nBase + wn + j * 16 + l15;
                    C[(size_t)row * Nc + col] = (unsigned short)brne(acc[i][j][r]);
                }
            }
        }
    }
}

// ---------------- propagation, bf16 tables ----------------
// Y[i,:] = sum_e w_e * X[src_e,:] + dinv[i]^2 * X[i,:] (+bias, relu)
// 256 features: lane owns 4 (uint2 = 4 bf16). Row = 64 uint2. Output bf16.
__global__ void k_prop256b(const unsigned int* __restrict__ X2,
                           const int* __restrict__ rowptr,
                           const int* __restrict__ es, const float* __restrict__ ew,
                           const float* __restrict__ dinv, const float* __restrict__ bias,
                           unsigned int* __restrict__ Y2, int n) {
    const int wid = (int)((blockIdx.x * blockDim.x + threadIdx.x) >> 6);
    const int lane = threadIdx.x & 63;
    if (wid >= n) return;
    const uint2* X = (const uint2*)X2;
    const float di = dinv[wid];
    const float ws = di * di;
    uint2 v = X[(size_t)wid * 64 + lane];
    float a0 = blo(v.x) * ws, a1 = bhi(v.x) * ws, a2 = blo(v.y) * ws, a3 = bhi(v.y) * ws;
    const int beg = rowptr[wid], end = rowptr[wid + 1];
    int j = beg;
    for (; j + 1 < end; j += 2) {
        const int s0 = es[j], s1 = es[j + 1];
        const float w0 = ew[j], w1 = ew[j + 1];
        const uint2 u0 = X[(size_t)s0 * 64 + lane];
        const uint2 u1 = X[(size_t)s1 * 64 + lane];
        a0 += blo(u0.x) * w0 + blo(u1.x) * w1;
        a1 += bhi(u0.x) * w0 + bhi(u1.x) * w1;
        a2 += blo(u0.y) * w0 + blo(u1.y) * w1;
        a3 += bhi(u0.y) * w0 + bhi(u1.y) * w1;
    }
    if (j < end) {
        const int s0 = es[j];
        const float w0 = ew[j];
        const uint2 u0 = X[(size_t)s0 * 64 + lane];
        a0 += blo(u0.x) * w0; a1 += bhi(u0.x) * w0;
        a2 += blo(u0.y) * w0; a3 += bhi(u0.y) * w0;
    }
    const float4 b = ((const float4*)bias)[lane];
    a0 = fmaxf(a0 + b.x, 0.f); a1 = fmaxf(a1 + b.y, 0.f);
    a2 = fmaxf(a2 + b.z, 0.f); a3 = fmaxf(a3 + b.w, 0.f);
    uint2 p;
    p.x = brne(a0) | (brne(a1) << 16);
    p.y = brne(a2) | (brne(a3) << 16);
    ((uint2*)Y2)[(size_t)wid * 64 + lane] = p;
}

// 128 features: lane owns 2 bf16 (one uint). Row = 64 uints / 64 float2.
// (round-2 bug was stride 32 here — must be 64)
__global__ void k_prop128b(const unsigned int* __restrict__ X,
                           const int* __restrict__ rowptr,
                           const int* __restrict__ es, const float* __restrict__ ew,
                           const float* __restrict__ dinv, const float* __restrict__ bias,
                           float* __restrict__ Yout, int n) {
    const int wid = (int)((blockIdx.x * blockDim.x + threadIdx.x) >> 6);
    const int lane = threadIdx.x & 63;
    if (wid >= n) return;
    const float di = dinv[wid];
    const float ws = di * di;
    unsigned int v = X[(size_t)wid * 64 + lane];
    float a0 = blo(v) * ws, a1 = bhi(v) * ws;
    const int beg = rowptr[wid], end = rowptr[wid + 1];
    int j = beg;
    for (; j + 1 < end; j += 2) {
        const int s0 = es[j], s1 = es[j + 1];
        const float w0 = ew[j], w1 = ew[j + 1];
        const unsigned int u0 = X[(size_t)s0 * 64 + lane];
        const unsigned int u1 = X[(size_t)s1 * 64 + lane];
        a0 += blo(u0) * w0 + blo(u1) * w1;
        a1 += bhi(u0) * w0 + bhi(u1) * w1;
    }
    if (j < end) {
        const int s0 = es[j];
        const float w0 = ew[j];
        const unsigned int u0 = X[(size_t)s0 * 64 + lane];
        a0 += blo(u0) * w0; a1 += bhi(u0) * w0;
    }
    const float2 b = ((const float2*)bias)[lane];
    float2 o = make_float2(a0 + b.x, a1 + b.y);
    ((float2*)Yout)[(size_t)wid * 64 + lane] = o;
}

extern "C" void kernel_launch(void* const* d_in, const int* in_sizes, int n_in,
                              void* d_out, int out_size, void* d_ws, size_t ws_size,
                              hipStream_t stream) {
    const float* x  = (const float*)d_in[0];
    const int*   ei = (const int*)d_in[1];
    const float* W1 = (const float*)d_in[2];
    const float* b1 = (const float*)d_in[3];
    const float* W2 = (const float*)d_in[4];
    const float* b2 = (const float*)d_in[5];
    float* out = (float*)d_out;

    const int n = in_sizes[0] / 256;  // 50000
    const int e = in_sizes[1] / 2;    // 1600000
    const int* src = ei;
    const int* dst = ei + e;

    char* wsp = (char*)d_ws;
    size_t off = 0;
    auto alloc = [&](size_t bytes) -> char* {
        char* p = wsp + off;
        off += (bytes + 511) & ~(size_t)511;
        return p;
    };
    int*   cnt    = (int*)alloc(sizeof(int) * n);
    float* dinv   = (float*)alloc(sizeof(float) * n);
    int*   rowptr = (int*)alloc(sizeof(int) * (n + 1));
    int*   part   = (int*)alloc(sizeof(int) * 256);
    int*   es     = (int*)alloc(sizeof(int) * e);
    float* ewt    = (float*)alloc(sizeof(float) * e);
    unsigned short* xb  = (unsigned short*)alloc(2ull * n * 256);   // bf16 x
    unsigned short* W1t = (unsigned short*)alloc(2ull * 256 * 256); // [N][K]
    unsigned short* W2t = (unsigned short*)alloc(2ull * 128 * 256); // [N][K]
    unsigned short* T1  = (unsigned short*)alloc(2ull * n * 256);   // x@W1 bf16
    unsigned short* H   = (unsigned short*)alloc(2ull * n * 256);   // relu(prop+b1) bf16
    unsigned short* T2  = (unsigned short*)alloc(2ull * n * 128);   // H@W2 bf16

    const int nb_n = (n + 255) / 256;
    const int nb_e = (e + 255) / 256;

    // ---- CSR build ----
    k_zero<<<nb_n, 256, 0, stream>>>(cnt, n);
    k_hist<<<nb_e, 256, 0, stream>>>(dst, cnt, e);
    k_dinv<<<nb_n, 256, 0, stream>>>(cnt, dinv, n);
    k_scan1<<<nb_n, 256, 0, stream>>>(cnt, rowptr, part, n);
    k_scan2<<<1, 256, 0, stream>>>(part, nb_n);
    k_scan3<<<nb_n, 256, 0, stream>>>(rowptr, part, cnt, n, e);
    k_scatter<<<nb_e, 256, 0, stream>>>(src, dst, dinv, cnt, es, ewt, e);

    // ---- dtype prep ----
    const int total4 = n * 256 / 4;
    k_cast_x<<<(total4 + 255) / 256, 256, 0, stream>>>(x, (unsigned int*)xb, total4);
    k_tW<<<(256 * 256 + 255) / 256, 256, 0, stream>>>(W1, W1t, 256 * 256, 8);
    k_tW<<<(256 * 128 + 255) / 256, 256, 0, stream>>>(W2, W2t, 256 * 128, 7);

    // ---- layer 1 ----
    dim3 g1((n + 127) / 128, 2);
    k_gemm_bf16<<<g1, 256, 0, stream>>>(xb, W1t, T1, n, 256);
    k_prop256b<<<(n + 3) / 4, 256, 0, stream>>>((const unsigned int*)T1, rowptr, es, ewt,
                                                dinv, b1, (unsigned int*)H, n);

    // ---- layer 2 ----
    dim3 g2((n + 127) / 128, 1);
    k_gemm_bf16<<<g2, 256, 0, stream>>>(H, W2t, T2, n, 128);
    k_prop128b<<<(n + 3) / 4, 256, 0, stream>>>((const unsigned int*)T2, rowptr, es, ewt,
                                                dinv, b2, out, n);
}

// Round 5
// 508.623 us; speedup vs baseline: 1.4883x; 1.0093x over previous
//
#include <hip/hip_runtime.h>

typedef short s16x8 __attribute__((ext_vector_type(8)));
typedef float f32x4 __attribute__((ext_vector_type(4)));

// ---------- bf16 helpers (bit-level, RNE) ----------
__device__ __forceinline__ unsigned int brne(float f) {
    unsigned int u = __float_as_uint(f);
    return (u + 0x7FFFu + ((u >> 16) & 1u)) >> 16;   // bf16 bits in low 16
}
__device__ __forceinline__ float blo(unsigned int u) { return __uint_as_float(u << 16); }
__device__ __forceinline__ float bhi(unsigned int u) { return __uint_as_float(u & 0xFFFF0000u); }

// accumulate 8 bf16 lanes of a uint4 row piece, scaled by wt
__device__ __forceinline__ void acc8(float* a, const uint4 u, const float wt) {
    a[0] += blo(u.x) * wt; a[1] += bhi(u.x) * wt;
    a[2] += blo(u.y) * wt; a[3] += bhi(u.y) * wt;
    a[4] += blo(u.z) * wt; a[5] += bhi(u.z) * wt;
    a[6] += blo(u.w) * wt; a[7] += bhi(u.w) * wt;
}

// ---------------- graph build ----------------
__global__ void k_hist(const int* __restrict__ dst, int* __restrict__ cnt, int e) {
    int i = blockIdx.x * blockDim.x + threadIdx.x;
    if (i < e) atomicAdd(&cnt[dst[i]], 1);
}

__global__ void k_dinv(const int* __restrict__ cnt, float* __restrict__ dinv, int n) {
    int i = blockIdx.x * blockDim.x + threadIdx.x;
    if (i < n) dinv[i] = rsqrtf((float)(cnt[i] + 1));  // deg includes self-loop
}

__global__ void k_scan1(const int* __restrict__ cnt, int* __restrict__ rowptr,
                        int* __restrict__ part, int n) {
    __shared__ int sh[256];
    int tid = threadIdx.x;
    int i = blockIdx.x * 256 + tid;
    int v = (i < n) ? cnt[i] : 0;
    int x = v;
    sh[tid] = x;
    __syncthreads();
    for (int off = 1; off < 256; off <<= 1) {
        int t = (tid >= off) ? sh[tid - off] : 0;
        __syncthreads();
        if (tid >= off) { x += t; sh[tid] = x; }
        __syncthreads();
    }
    if (i < n) rowptr[i] = x - v;
    if (tid == 255) part[blockIdx.x] = x;
}

__global__ void k_scan2(int* __restrict__ part, int nb) {
    __shared__ int sh[256];
    int tid = threadIdx.x;
    int v = (tid < nb) ? part[tid] : 0;
    int x = v;
    sh[tid] = x;
    __syncthreads();
    for (int off = 1; off < 256; off <<= 1) {
        int t = (tid >= off) ? sh[tid - off] : 0;
        __syncthreads();
        if (tid >= off) { x += t; sh[tid] = x; }
        __syncthreads();
    }
    if (tid < nb) part[tid] = x - v;
}

__global__ void k_scan3(int* __restrict__ rowptr, const int* __restrict__ part,
                        int* __restrict__ cursor, int n, int e) {
    int i = blockIdx.x * blockDim.x + threadIdx.x;
    if (i < n) {
        int r = rowptr[i] + part[i >> 8];
        rowptr[i] = r;
        cursor[i] = r;
    }
    if (i == 0) rowptr[n] = e;
}

__global__ void k_scatter(const int* __restrict__ src, const int* __restrict__ dst,
                          int* __restrict__ cursor, int* __restrict__ es, int e) {
    int i = blockIdx.x * blockDim.x + threadIdx.x;
    if (i < e) {
        int s = src[i], d = dst[i];
        int p = atomicAdd(&cursor[d], 1);
        es[p] = s;
    }
}

// ---------------- dtype prep ----------------
__global__ void k_cast_x(const float* __restrict__ x, unsigned int* __restrict__ xb2,
                         int total4) {
    int i = blockIdx.x * blockDim.x + threadIdx.x;
    if (i >= total4) return;
    float4 v = ((const float4*)x)[i];
    uint2 p;
    p.x = brne(v.x) | (brne(v.y) << 16);
    p.y = brne(v.z) | (brne(v.w) << 16);
    ((uint2*)xb2)[i] = p;
}

// W[K][N] fp32 -> Wt[N][K] bf16 (K=256, N = 1<<nshift)
__global__ void k_tW(const float* __restrict__ W, unsigned short* __restrict__ Wt,
                     int total, int nshift) {
    int t = blockIdx.x * blockDim.x + threadIdx.x;
    if (t >= total) return;
    int k = t >> nshift;
    int nn = t & ((1 << nshift) - 1);
    Wt[(size_t)nn * 256 + k] = (unsigned short)brne(W[t]);
}

// ---------------- bf16 MFMA GEMM: C[M,Nc] = A[M,256] @ Bt[Nc,256]^T ----------------
// 128x128 block tile, 4 waves (2x2 of 64x64), BK=32, K=256 fixed.
// LDS row padded to 40 shorts (80 B) -> fragment reads land 2-way on banks (free).
#define LP 40
__global__ __launch_bounds__(256) void k_gemm_bf16(const unsigned short* __restrict__ A,
                                                   const unsigned short* __restrict__ Bt,
                                                   unsigned short* __restrict__ C,
                                                   int M, int Nc) {
    __shared__ unsigned short As[128 * LP];
    __shared__ unsigned short Bs[128 * LP];

    const int tid = threadIdx.x;
    const int wave = tid >> 6, lane = tid & 63;
    const int wm = (wave >> 1) * 64, wn = (wave & 1) * 64;
    const int l15 = lane & 15, quad = lane >> 4;
    const int mBase = blockIdx.x * 128, nBase = blockIdx.y * 128;

    f32x4 acc[4][4];
#pragma unroll
    for (int i = 0; i < 4; i++)
#pragma unroll
        for (int j = 0; j < 4; j++) acc[i][j] = (f32x4){0.f, 0.f, 0.f, 0.f};

    const int c0 = tid, c1 = 256 + tid;
    const int r0 = c0 >> 2, kc0 = c0 & 3;
    const int r1 = c1 >> 2, kc1 = c1 & 3;
    int am0 = mBase + r0; if (am0 >= M) am0 = M - 1;
    int am1 = mBase + r1; if (am1 >= M) am1 = M - 1;
    const uint4* Ap0 = (const uint4*)A + (size_t)am0 * 32 + kc0;
    const uint4* Ap1 = (const uint4*)A + (size_t)am1 * 32 + kc1;
    const uint4* Bp0 = (const uint4*)Bt + (size_t)(nBase + r0) * 32 + kc0;
    const uint4* Bp1 = (const uint4*)Bt + (size_t)(nBase + r1) * 32 + kc1;

    for (int kt = 0; kt < 8; ++kt) {
        uint4 a0 = Ap0[kt * 4];
        uint4 a1 = Ap1[kt * 4];
        uint4 b0 = Bp0[kt * 4];
        uint4 b1 = Bp1[kt * 4];
        __syncthreads();
        *(uint4*)&As[r0 * LP + kc0 * 8] = a0;
        *(uint4*)&As[r1 * LP + kc1 * 8] = a1;
        *(uint4*)&Bs[r0 * LP + kc0 * 8] = b0;
        *(uint4*)&Bs[r1 * LP + kc1 * 8] = b1;
        __syncthreads();

        s16x8 af[4], bf[4];
#pragma unroll
        for (int i = 0; i < 4; i++)
            af[i] = *(const s16x8*)&As[(wm + i * 16 + l15) * LP + quad * 8];
#pragma unroll
        for (int j = 0; j < 4; j++)
            bf[j] = *(const s16x8*)&Bs[(wn + j * 16 + l15) * LP + quad * 8];
#pragma unroll
        for (int i = 0; i < 4; i++)
#pragma unroll
            for (int j = 0; j < 4; j++)
                acc[i][j] = __builtin_amdgcn_mfma_f32_16x16x32_bf16(af[i], bf[j], acc[i][j], 0, 0, 0);
    }

#pragma unroll
    for (int i = 0; i < 4; i++) {
        const int rowb = mBase + wm + i * 16 + quad * 4;
#pragma unroll
        for (int r = 0; r < 4; r++) {
            const int row = rowb + r;
            if (row < M) {
#pragma unroll
                for (int j = 0; j < 4; j++) {
                    const int col = nBase + wn + j * 16 + l15;
                    C[(size_t)row * Nc + col] = (unsigned short)brne(acc[i][j][r]);
                }
            }
        }
    }
}

// ---------------- propagation, bf16 tables, uint4 gathers ----------------
// 256 feats = 32 uint4/row. Half-wave (32 lanes x 16B) per edge -> 2 edges in
// flight; unroll 2 -> 4. Cross-half shfl_xor(32) reduce; half 0 stores bf16.
__global__ void k_prop256b(const uint4* __restrict__ X4,
                           const int* __restrict__ rowptr,
                           const int* __restrict__ es,
                           const float* __restrict__ dinv,
                           const float* __restrict__ bias,
                           uint4* __restrict__ Y4, int n) {
    const int wid = (int)((blockIdx.x * blockDim.x + threadIdx.x) >> 6);
    const int lane = threadIdx.x & 63;
    const int half = lane >> 5, l32 = lane & 31;
    if (wid >= n) return;
    const float dd = dinv[wid];
    float a[8];
    {
        const uint4 v = X4[(size_t)wid * 32 + l32];
        const float ws = (half == 0) ? dd * dd : 0.f;
        a[0] = blo(v.x) * ws; a[1] = bhi(v.x) * ws;
        a[2] = blo(v.y) * ws; a[3] = bhi(v.y) * ws;
        a[4] = blo(v.z) * ws; a[5] = bhi(v.z) * ws;
        a[6] = blo(v.w) * ws; a[7] = bhi(v.w) * ws;
    }
    const int beg = rowptr[wid], end = rowptr[wid + 1];
    int j = beg + half;
    for (; j + 2 < end; j += 4) {
        const int s0 = es[j], s1 = es[j + 2];
        const float w0 = dinv[s0] * dd, w1 = dinv[s1] * dd;
        const uint4 u0 = X4[(size_t)s0 * 32 + l32];
        const uint4 u1 = X4[(size_t)s1 * 32 + l32];
        acc8(a, u0, w0);
        acc8(a, u1, w1);
    }
    if (j < end) {
        const int s0 = es[j];
        const float w0 = dinv[s0] * dd;
        const uint4 u0 = X4[(size_t)s0 * 32 + l32];
        acc8(a, u0, w0);
    }
#pragma unroll
    for (int k = 0; k < 8; k++) a[k] += __shfl_xor(a[k], 32);
    if (half == 0) {
        const float4 b0 = ((const float4*)bias)[l32 * 2];
        const float4 b1 = ((const float4*)bias)[l32 * 2 + 1];
        a[0] = fmaxf(a[0] + b0.x, 0.f); a[1] = fmaxf(a[1] + b0.y, 0.f);
        a[2] = fmaxf(a[2] + b0.z, 0.f); a[3] = fmaxf(a[3] + b0.w, 0.f);
        a[4] = fmaxf(a[4] + b1.x, 0.f); a[5] = fmaxf(a[5] + b1.y, 0.f);
        a[6] = fmaxf(a[6] + b1.z, 0.f); a[7] = fmaxf(a[7] + b1.w, 0.f);
        uint4 p;
        p.x = brne(a[0]) | (brne(a[1]) << 16);
        p.y = brne(a[2]) | (brne(a[3]) << 16);
        p.z = brne(a[4]) | (brne(a[5]) << 16);
        p.w = brne(a[6]) | (brne(a[7]) << 16);
        Y4[(size_t)wid * 32 + l32] = p;
    }
}

// 128 feats = 16 uint4/row. Quarter-wave (16 lanes x 16B) per edge -> 4 edges
// in flight; unroll 2 -> 8. shfl_xor(16)+shfl_xor(32) reduce; quad 0 stores fp32.
__global__ void k_prop128b(const uint4* __restrict__ X4,
                           const int* __restrict__ rowptr,
                           const int* __restrict__ es,
                           const float* __restrict__ dinv,
                           const float* __restrict__ bias,
                           float* __restrict__ Yout, int n) {
    const int wid = (int)((blockIdx.x * blockDim.x + threadIdx.x) >> 6);
    const int lane = threadIdx.x & 63;
    const int quad = lane >> 4, l16 = lane & 15;
    if (wid >= n) return;
    const float dd = dinv[wid];
    float a[8];
    {
        const uint4 v = X4[(size_t)wid * 16 + l16];
        const float ws = (quad == 0) ? dd * dd : 0.f;
        a[0] = blo(v.x) * ws; a[1] = bhi(v.x) * ws;
        a[2] = blo(v.y) * ws; a[3] = bhi(v.y) * ws;
        a[4] = blo(v.z) * ws; a[5] = bhi(v.z) * ws;
        a[6] = blo(v.w) * ws; a[7] = bhi(v.w) * ws;
    }
    const int beg = rowptr[wid], end = rowptr[wid + 1];
    int j = beg + quad;
    for (; j + 4 < end; j += 8) {
        const int s0 = es[j], s1 = es[j + 4];
        const float w0 = dinv[s0] * dd, w1 = dinv[s1] * dd;
        const uint4 u0 = X4[(size_t)s0 * 16 + l16];
        const uint4 u1 = X4[(size_t)s1 * 16 + l16];
        acc8(a, u0, w0);
        acc8(a, u1, w1);
    }
    if (j < end) {
        const int s0 = es[j];
        const float w0 = dinv[s0] * dd;
        const uint4 u0 = X4[(size_t)s0 * 16 + l16];
        acc8(a, u0, w0);
    }
#pragma unroll
    for (int k = 0; k < 8; k++) {
        a[k] += __shfl_xor(a[k], 16);
        a[k] += __shfl_xor(a[k], 32);
    }
    if (quad == 0) {
        const float4 b0 = ((const float4*)bias)[l16 * 2];
        const float4 b1 = ((const float4*)bias)[l16 * 2 + 1];
        float4 o0 = make_float4(a[0] + b0.x, a[1] + b0.y, a[2] + b0.z, a[3] + b0.w);
        float4 o1 = make_float4(a[4] + b1.x, a[5] + b1.y, a[6] + b1.z, a[7] + b1.w);
        ((float4*)Yout)[(size_t)wid * 32 + l16 * 2] = o0;
        ((float4*)Yout)[(size_t)wid * 32 + l16 * 2 + 1] = o1;
    }
}

extern "C" void kernel_launch(void* const* d_in, const int* in_sizes, int n_in,
                              void* d_out, int out_size, void* d_ws, size_t ws_size,
                              hipStream_t stream) {
    const float* x  = (const float*)d_in[0];
    const int*   ei = (const int*)d_in[1];
    const float* W1 = (const float*)d_in[2];
    const float* b1 = (const float*)d_in[3];
    const float* W2 = (const float*)d_in[4];
    const float* b2 = (const float*)d_in[5];
    float* out = (float*)d_out;

    const int n = in_sizes[0] / 256;  // 50000
    const int e = in_sizes[1] / 2;    // 1600000
    const int* src = ei;
    const int* dst = ei + e;

    char* wsp = (char*)d_ws;
    size_t off = 0;
    auto alloc = [&](size_t bytes) -> char* {
        char* p = wsp + off;
        off += (bytes + 511) & ~(size_t)511;
        return p;
    };
    int*   cnt    = (int*)alloc(sizeof(int) * n);
    float* dinv   = (float*)alloc(sizeof(float) * n);
    int*   rowptr = (int*)alloc(sizeof(int) * (n + 1));
    int*   part   = (int*)alloc(sizeof(int) * 256);
    int*   es     = (int*)alloc(sizeof(int) * e);
    unsigned short* xb  = (unsigned short*)alloc(2ull * n * 256);   // bf16 x
    unsigned short* W1t = (unsigned short*)alloc(2ull * 256 * 256); // [N][K]
    unsigned short* W2t = (unsigned short*)alloc(2ull * 128 * 256); // [N][K]
    unsigned short* T1  = (unsigned short*)alloc(2ull * n * 256);   // x@W1 bf16
    unsigned short* H   = (unsigned short*)alloc(2ull * n * 256);   // relu(prop+b1) bf16
    unsigned short* T2  = (unsigned short*)alloc(2ull * n * 128);   // H@W2 bf16

    const int nb_n = (n + 255) / 256;
    const int nb_e = (e + 255) / 256;

    // ---- CSR build ----
    (void)hipMemsetAsync(cnt, 0, sizeof(int) * n, stream);
    k_hist<<<nb_e, 256, 0, stream>>>(dst, cnt, e);
    k_dinv<<<nb_n, 256, 0, stream>>>(cnt, dinv, n);
    k_scan1<<<nb_n, 256, 0, stream>>>(cnt, rowptr, part, n);
    k_scan2<<<1, 256, 0, stream>>>(part, nb_n);
    k_scan3<<<nb_n, 256, 0, stream>>>(rowptr, part, cnt, n, e);
    k_scatter<<<nb_e, 256, 0, stream>>>(src, dst, cnt, es, e);

    // ---- dtype prep ----
    const int total4 = n * 256 / 4;
    k_cast_x<<<(total4 + 255) / 256, 256, 0, stream>>>(x, (unsigned int*)xb, total4);
    k_tW<<<(256 * 256 + 255) / 256, 256, 0, stream>>>(W1, W1t, 256 * 256, 8);
    k_tW<<<(256 * 128 + 255) / 256, 256, 0, stream>>>(W2, W2t, 256 * 128, 7);

    // ---- layer 1 ----
    dim3 g1((n + 127) / 128, 2);
    k_gemm_bf16<<<g1, 256, 0, stream>>>(xb, W1t, T1, n, 256);
    k_prop256b<<<(n + 3) / 4, 256, 0, stream>>>((const uint4*)T1, rowptr, es,
                                                dinv, b1, (uint4*)H, n);

    // ---- layer 2 ----
    dim3 g2((n + 127) / 128, 1);
    k_gemm_bf16<<<g2, 256, 0, stream>>>(H, W2t, T2, n, 128);
    k_prop128b<<<(n + 3) / 4, 256, 0, stream>>>((const uint4*)T2, rowptr, es,
                                                dinv, b2, out, n);
}

// Round 6
// 387.917 us; speedup vs baseline: 1.9515x; 1.3112x over previous
//
#include <hip/hip_runtime.h>

typedef short s16x8 __attribute__((ext_vector_type(8)));
typedef float f32x4 __attribute__((ext_vector_type(4)));

#define TILE 2048  // edges per block in binning passes (256 thr x 8)

// ---------- bf16 helpers (bit-level, RNE) ----------
__device__ __forceinline__ unsigned int brne(float f) {
    unsigned int u = __float_as_uint(f);
    return (u + 0x7FFFu + ((u >> 16) & 1u)) >> 16;   // bf16 bits in low 16
}
__device__ __forceinline__ float blo(unsigned int u) { return __uint_as_float(u << 16); }
__device__ __forceinline__ float bhi(unsigned int u) { return __uint_as_float(u & 0xFFFF0000u); }

__device__ __forceinline__ void acc8(float* a, const uint4 u, const float wt) {
    a[0] += blo(u.x) * wt; a[1] += bhi(u.x) * wt;
    a[2] += blo(u.y) * wt; a[3] += bhi(u.y) * wt;
    a[4] += blo(u.z) * wt; a[5] += bhi(u.z) * wt;
    a[6] += blo(u.w) * wt; a[7] += bhi(u.w) * wt;
}

// ---------------- binned CSR build ----------------
// bucket = dst >> 8 (256 nodes per bucket, nb = ceil(n/256) <= 256)

__global__ void k_bhist(const int* __restrict__ dst, int* __restrict__ bucket_cnt,
                        int e, int nb) {
    __shared__ int h[256];
    const int tid = threadIdx.x;
    h[tid] = 0;
    __syncthreads();
    const int base = blockIdx.x * TILE + tid;
#pragma unroll
    for (int k = 0; k < 8; k++) {
        const int i = base + k * 256;
        if (i < e) atomicAdd(&h[dst[i] >> 8], 1);
    }
    __syncthreads();
    if (tid < nb && h[tid]) atomicAdd(&bucket_cnt[tid], h[tid]);
}

__global__ void k_bscan(const int* __restrict__ bucket_cnt, int* __restrict__ bucket_base,
                        int* __restrict__ bucket_cursor, int nb, int e) {
    __shared__ int sh[256];
    const int tid = threadIdx.x;
    const int v = (tid < nb) ? bucket_cnt[tid] : 0;
    int x = v;
    sh[tid] = x;
    __syncthreads();
    for (int off = 1; off < 256; off <<= 1) {
        const int t = (tid >= off) ? sh[tid - off] : 0;
        __syncthreads();
        if (tid >= off) { x += t; sh[tid] = x; }
        __syncthreads();
    }
    if (tid < nb) { bucket_base[tid] = x - v; bucket_cursor[tid] = x - v; }
    if (tid == 0) bucket_base[nb] = e;
}

// scatter (src,dst) pairs into coarse buckets; block reserves contiguous space
// per bucket so global writes are line-dense.
__global__ void k_bscatter(const int* __restrict__ src, const int* __restrict__ dst,
                           int* __restrict__ bucket_cursor, uint2* __restrict__ eb, int e) {
    __shared__ int h[256], hbase[256], h2[256];
    const int tid = threadIdx.x;
    h[tid] = 0; h2[tid] = 0;
    __syncthreads();
    const int base = blockIdx.x * TILE + tid;
    int s[8], d[8], b[8];
    bool val[8];
#pragma unroll
    for (int k = 0; k < 8; k++) {
        const int i = base + k * 256;
        val[k] = i < e;
        if (val[k]) {
            s[k] = src[i]; d[k] = dst[i]; b[k] = d[k] >> 8;
            atomicAdd(&h[b[k]], 1);
        }
    }
    __syncthreads();
    if (h[tid]) hbase[tid] = atomicAdd(&bucket_cursor[tid], h[tid]);
    __syncthreads();
#pragma unroll
    for (int k = 0; k < 8; k++) {
        if (val[k]) {
            const int off = atomicAdd(&h2[b[k]], 1);
            eb[hbase[b[k]] + off] = make_uint2((unsigned)s[k], (unsigned)d[k]);
        }
    }
}

// per-bucket exact per-node histogram -> cnt + dinv (replaces global atomic hist)
__global__ void k_nhist(const uint2* __restrict__ eb, const int* __restrict__ bucket_base,
                        int* __restrict__ cnt, float* __restrict__ dinv, int n) {
    __shared__ int c[256];
    const int tid = threadIdx.x, b = blockIdx.x;
    c[tid] = 0;
    __syncthreads();
    const int beg = bucket_base[b], end = bucket_base[b + 1];
    for (int i = beg + tid; i < end; i += 256)
        atomicAdd(&c[eb[i].y & 255], 1);
    __syncthreads();
    const int node = b * 256 + tid;
    if (node < n) {
        cnt[node] = c[tid];
        dinv[node] = rsqrtf((float)(c[tid] + 1));  // deg includes self-loop
    }
}

__global__ void k_scan1(const int* __restrict__ cnt, int* __restrict__ rowptr,
                        int* __restrict__ part, int n) {
    __shared__ int sh[256];
    int tid = threadIdx.x;
    int i = blockIdx.x * 256 + tid;
    int v = (i < n) ? cnt[i] : 0;
    int x = v;
    sh[tid] = x;
    __syncthreads();
    for (int off = 1; off < 256; off <<= 1) {
        int t = (tid >= off) ? sh[tid - off] : 0;
        __syncthreads();
        if (tid >= off) { x += t; sh[tid] = x; }
        __syncthreads();
    }
    if (i < n) rowptr[i] = x - v;
    if (tid == 255) part[blockIdx.x] = x;
}

__global__ void k_scan2(int* __restrict__ part, int nb) {
    __shared__ int sh[256];
    int tid = threadIdx.x;
    int v = (tid < nb) ? part[tid] : 0;
    int x = v;
    sh[tid] = x;
    __syncthreads();
    for (int off = 1; off < 256; off <<= 1) {
        int t = (tid >= off) ? sh[tid - off] : 0;
        __syncthreads();
        if (tid >= off) { x += t; sh[tid] = x; }
        __syncthreads();
    }
    if (tid < nb) part[tid] = x - v;
}

__global__ void k_scan3(int* __restrict__ rowptr, const int* __restrict__ part,
                        int n, int e) {
    int i = blockIdx.x * blockDim.x + threadIdx.x;
    if (i < n) rowptr[i] = rowptr[i] + part[i >> 8];
    if (i == 0) rowptr[n] = e;
}

// final placement: one block per bucket; all writes to a node segment come from
// this block only -> lines fill inside one L2 and evict once.
__global__ void k_place(const uint2* __restrict__ eb, const int* __restrict__ bucket_base,
                        const int* __restrict__ rowptr, int* __restrict__ es, int n) {
    __shared__ int offs[256];
    const int tid = threadIdx.x, b = blockIdx.x;
    offs[tid] = 0;
    __syncthreads();
    const int beg = bucket_base[b], end = bucket_base[b + 1];
    for (int i = beg + tid; i < end; i += 256) {
        const uint2 ed = eb[i];
        const int d = (int)ed.y;
        const int local = atomicAdd(&offs[d & 255], 1);
        es[rowptr[d] + local] = (int)ed.x;
    }
}

// ---------------- dtype prep ----------------
__global__ void k_cast_x(const float* __restrict__ x, unsigned int* __restrict__ xb2,
                         int total4) {
    int i = blockIdx.x * blockDim.x + threadIdx.x;
    if (i >= total4) return;
    float4 v = ((const float4*)x)[i];
    uint2 p;
    p.x = brne(v.x) | (brne(v.y) << 16);
    p.y = brne(v.z) | (brne(v.w) << 16);
    ((uint2*)xb2)[i] = p;
}

// W[K][N] fp32 -> Wt[N][K] bf16 (K=256, N = 1<<nshift)
__global__ void k_tW(const float* __restrict__ W, unsigned short* __restrict__ Wt,
                     int total, int nshift) {
    int t = blockIdx.x * blockDim.x + threadIdx.x;
    if (t >= total) return;
    int k = t >> nshift;
    int nn = t & ((1 << nshift) - 1);
    Wt[(size_t)nn * 256 + k] = (unsigned short)brne(W[t]);
}

// ---------------- bf16 MFMA GEMM: C[M,Nc] = A[M,256] @ Bt[Nc,256]^T ----------------
#define LP 40
__global__ __launch_bounds__(256) void k_gemm_bf16(const unsigned short* __restrict__ A,
                                                   const unsigned short* __restrict__ Bt,
                                                   unsigned short* __restrict__ C,
                                                   int M, int Nc) {
    __shared__ unsigned short As[128 * LP];
    __shared__ unsigned short Bs[128 * LP];

    const int tid = threadIdx.x;
    const int wave = tid >> 6, lane = tid & 63;
    const int wm = (wave >> 1) * 64, wn = (wave & 1) * 64;
    const int l15 = lane & 15, quad = lane >> 4;
    const int mBase = blockIdx.x * 128, nBase = blockIdx.y * 128;

    f32x4 acc[4][4];
#pragma unroll
    for (int i = 0; i < 4; i++)
#pragma unroll
        for (int j = 0; j < 4; j++) acc[i][j] = (f32x4){0.f, 0.f, 0.f, 0.f};

    const int c0 = tid, c1 = 256 + tid;
    const int r0 = c0 >> 2, kc0 = c0 & 3;
    const int r1 = c1 >> 2, kc1 = c1 & 3;
    int am0 = mBase + r0; if (am0 >= M) am0 = M - 1;
    int am1 = mBase + r1; if (am1 >= M) am1 = M - 1;
    const uint4* Ap0 = (const uint4*)A + (size_t)am0 * 32 + kc0;
    const uint4* Ap1 = (const uint4*)A + (size_t)am1 * 32 + kc1;
    const uint4* Bp0 = (const uint4*)Bt + (size_t)(nBase + r0) * 32 + kc0;
    const uint4* Bp1 = (const uint4*)Bt + (size_t)(nBase + r1) * 32 + kc1;

    for (int kt = 0; kt < 8; ++kt) {
        uint4 a0 = Ap0[kt * 4];
        uint4 a1 = Ap1[kt * 4];
        uint4 b0 = Bp0[kt * 4];
        uint4 b1 = Bp1[kt * 4];
        __syncthreads();
        *(uint4*)&As[r0 * LP + kc0 * 8] = a0;
        *(uint4*)&As[r1 * LP + kc1 * 8] = a1;
        *(uint4*)&Bs[r0 * LP + kc0 * 8] = b0;
        *(uint4*)&Bs[r1 * LP + kc1 * 8] = b1;
        __syncthreads();

        s16x8 af[4], bf[4];
#pragma unroll
        for (int i = 0; i < 4; i++)
            af[i] = *(const s16x8*)&As[(wm + i * 16 + l15) * LP + quad * 8];
#pragma unroll
        for (int j = 0; j < 4; j++)
            bf[j] = *(const s16x8*)&Bs[(wn + j * 16 + l15) * LP + quad * 8];
#pragma unroll
        for (int i = 0; i < 4; i++)
#pragma unroll
            for (int j = 0; j < 4; j++)
                acc[i][j] = __builtin_amdgcn_mfma_f32_16x16x32_bf16(af[i], bf[j], acc[i][j], 0, 0, 0);
    }

#pragma unroll
    for (int i = 0; i < 4; i++) {
        const int rowb = mBase + wm + i * 16 + quad * 4;
#pragma unroll
        for (int r = 0; r < 4; r++) {
            const int row = rowb + r;
            if (row < M) {
#pragma unroll
                for (int j = 0; j < 4; j++) {
                    const int col = nBase + wn + j * 16 + l15;
                    C[(size_t)row * Nc + col] = (unsigned short)brne(acc[i][j][r]);
                }
            }
        }
    }
}

// ---------------- propagation, bf16 tables, uint4 gathers ----------------
__global__ void k_prop256b(const uint4* __restrict__ X4,
                           const int* __restrict__ rowptr,
                           const int* __restrict__ es,
                           const float* __restrict__ dinv,
                           const float* __restrict__ bias,
                           uint4* __restrict__ Y4, int n) {
    const int wid = (int)((blockIdx.x * blockDim.x + threadIdx.x) >> 6);
    const int lane = threadIdx.x & 63;
    const int half = lane >> 5, l32 = lane & 31;
    if (wid >= n) return;
    const float dd = dinv[wid];
    float a[8];
    {
        const uint4 v = X4[(size_t)wid * 32 + l32];
        const float ws = (half == 0) ? dd * dd : 0.f;
        a[0] = blo(v.x) * ws; a[1] = bhi(v.x) * ws;
        a[2] = blo(v.y) * ws; a[3] = bhi(v.y) * ws;
        a[4] = blo(v.z) * ws; a[5] = bhi(v.z) * ws;
        a[6] = blo(v.w) * ws; a[7] = bhi(v.w) * ws;
    }
    const int beg = rowptr[wid], end = rowptr[wid + 1];
    int j = beg + half;
    for (; j + 2 < end; j += 4) {
        const int s0 = es[j], s1 = es[j + 2];
        const float w0 = dinv[s0] * dd, w1 = dinv[s1] * dd;
        const uint4 u0 = X4[(size_t)s0 * 32 + l32];
        const uint4 u1 = X4[(size_t)s1 * 32 + l32];
        acc8(a, u0, w0);
        acc8(a, u1, w1);
    }
    if (j < end) {
        const int s0 = es[j];
        const float w0 = dinv[s0] * dd;
        const uint4 u0 = X4[(size_t)s0 * 32 + l32];
        acc8(a, u0, w0);
    }
#pragma unroll
    for (int k = 0; k < 8; k++) a[k] += __shfl_xor(a[k], 32);
    if (half == 0) {
        const float4 b0 = ((const float4*)bias)[l32 * 2];
        const float4 b1 = ((const float4*)bias)[l32 * 2 + 1];
        a[0] = fmaxf(a[0] + b0.x, 0.f); a[1] = fmaxf(a[1] + b0.y, 0.f);
        a[2] = fmaxf(a[2] + b0.z, 0.f); a[3] = fmaxf(a[3] + b0.w, 0.f);
        a[4] = fmaxf(a[4] + b1.x, 0.f); a[5] = fmaxf(a[5] + b1.y, 0.f);
        a[6] = fmaxf(a[6] + b1.z, 0.f); a[7] = fmaxf(a[7] + b1.w, 0.f);
        uint4 p;
        p.x = brne(a[0]) | (brne(a[1]) << 16);
        p.y = brne(a[2]) | (brne(a[3]) << 16);
        p.z = brne(a[4]) | (brne(a[5]) << 16);
        p.w = brne(a[6]) | (brne(a[7]) << 16);
        Y4[(size_t)wid * 32 + l32] = p;
    }
}

__global__ void k_prop128b(const uint4* __restrict__ X4,
                           const int* __restrict__ rowptr,
                           const int* __restrict__ es,
                           const float* __restrict__ dinv,
                           const float* __restrict__ bias,
                           float* __restrict__ Yout, int n) {
    const int wid = (int)((blockIdx.x * blockDim.x + threadIdx.x) >> 6);
    const int lane = threadIdx.x & 63;
    const int quad = lane >> 4, l16 = lane & 15;
    if (wid >= n) return;
    const float dd = dinv[wid];
    float a[8];
    {
        const uint4 v = X4[(size_t)wid * 16 + l16];
        const float ws = (quad == 0) ? dd * dd : 0.f;
        a[0] = blo(v.x) * ws; a[1] = bhi(v.x) * ws;
        a[2] = blo(v.y) * ws; a[3] = bhi(v.y) * ws;
        a[4] = blo(v.z) * ws; a[5] = bhi(v.z) * ws;
        a[6] = blo(v.w) * ws; a[7] = bhi(v.w) * ws;
    }
    const int beg = rowptr[wid], end = rowptr[wid + 1];
    int j = beg + quad;
    for (; j + 4 < end; j += 8) {
        const int s0 = es[j], s1 = es[j + 4];
        const float w0 = dinv[s0] * dd, w1 = dinv[s1] * dd;
        const uint4 u0 = X4[(size_t)s0 * 16 + l16];
        const uint4 u1 = X4[(size_t)s1 * 16 + l16];
        acc8(a, u0, w0);
        acc8(a, u1, w1);
    }
    if (j < end) {
        const int s0 = es[j];
        const float w0 = dinv[s0] * dd;
        const uint4 u0 = X4[(size_t)s0 * 16 + l16];
        acc8(a, u0, w0);
    }
#pragma unroll
    for (int k = 0; k < 8; k++) {
        a[k] += __shfl_xor(a[k], 16);
        a[k] += __shfl_xor(a[k], 32);
    }
    if (quad == 0) {
        const float4 b0 = ((const float4*)bias)[l16 * 2];
        const float4 b1 = ((const float4*)bias)[l16 * 2 + 1];
        float4 o0 = make_float4(a[0] + b0.x, a[1] + b0.y, a[2] + b0.z, a[3] + b0.w);
        float4 o1 = make_float4(a[4] + b1.x, a[5] + b1.y, a[6] + b1.z, a[7] + b1.w);
        ((float4*)Yout)[(size_t)wid * 32 + l16 * 2] = o0;
        ((float4*)Yout)[(size_t)wid * 32 + l16 * 2 + 1] = o1;
    }
}

extern "C" void kernel_launch(void* const* d_in, const int* in_sizes, int n_in,
                              void* d_out, int out_size, void* d_ws, size_t ws_size,
                              hipStream_t stream) {
    const float* x  = (const float*)d_in[0];
    const int*   ei = (const int*)d_in[1];
    const float* W1 = (const float*)d_in[2];
    const float* b1 = (const float*)d_in[3];
    const float* W2 = (const float*)d_in[4];
    const float* b2 = (const float*)d_in[5];
    float* out = (float*)d_out;

    const int n = in_sizes[0] / 256;  // 50000
    const int e = in_sizes[1] / 2;    // 1600000
    const int* src = ei;
    const int* dst = ei + e;
    const int nb = (n + 255) >> 8;    // 196 coarse buckets (<=256 required)

    char* wsp = (char*)d_ws;
    size_t off = 0;
    auto alloc = [&](size_t bytes) -> char* {
        char* p = wsp + off;
        off += (bytes + 511) & ~(size_t)511;
        return p;
    };
    int*   cnt     = (int*)alloc(sizeof(int) * n);
    float* dinv    = (float*)alloc(sizeof(float) * n);
    int*   rowptr  = (int*)alloc(sizeof(int) * (n + 1));
    int*   part    = (int*)alloc(sizeof(int) * 256);
    int*   bcnt    = (int*)alloc(sizeof(int) * 256);
    int*   bbase   = (int*)alloc(sizeof(int) * 257);
    int*   bcur    = (int*)alloc(sizeof(int) * 256);
    int*   es      = (int*)alloc(sizeof(int) * e);
    unsigned short* xb  = (unsigned short*)alloc(2ull * n * 256);   // bf16 x
    unsigned short* W1t = (unsigned short*)alloc(2ull * 256 * 256); // [N][K]
    unsigned short* W2t = (unsigned short*)alloc(2ull * 128 * 256); // [N][K]
    unsigned short* T1  = (unsigned short*)alloc(2ull * n * 256);   // x@W1 bf16
    unsigned short* H   = (unsigned short*)alloc(2ull * n * 256);   // relu(prop+b1) bf16
    unsigned short* T2  = (unsigned short*)alloc(2ull * n * 128);   // H@W2 bf16
    // eb (coarse-binned (src,dst) pairs, 8B*e) aliases H: build finishes
    // (k_place) before H is first written (prop256b).
    uint2* eb = (uint2*)H;

    const int nb_n = (n + 255) / 256;
    const int nb_t = (e + TILE - 1) / TILE;

    // ---- binned CSR build ----
    (void)hipMemsetAsync(bcnt, 0, sizeof(int) * 256, stream);
    k_bhist<<<nb_t, 256, 0, stream>>>(dst, bcnt, e, nb);
    k_bscan<<<1, 256, 0, stream>>>(bcnt, bbase, bcur, nb, e);
    k_bscatter<<<nb_t, 256, 0, stream>>>(src, dst, bcur, eb, e);
    k_nhist<<<nb, 256, 0, stream>>>(eb, bbase, cnt, dinv, n);
    k_scan1<<<nb_n, 256, 0, stream>>>(cnt, rowptr, part, n);
    k_scan2<<<1, 256, 0, stream>>>(part, nb_n);
    k_scan3<<<nb_n, 256, 0, stream>>>(rowptr, part, n, e);
    k_place<<<nb, 256, 0, stream>>>(eb, bbase, rowptr, es, n);

    // ---- dtype prep ----
    const int total4 = n * 256 / 4;
    k_cast_x<<<(total4 + 255) / 256, 256, 0, stream>>>(x, (unsigned int*)xb, total4);
    k_tW<<<(256 * 256 + 255) / 256, 256, 0, stream>>>(W1, W1t, 256 * 256, 8);
    k_tW<<<(256 * 128 + 255) / 256, 256, 0, stream>>>(W2, W2t, 256 * 128, 7);

    // ---- layer 1 ----
    dim3 g1((n + 127) / 128, 2);
    k_gemm_bf16<<<g1, 256, 0, stream>>>(xb, W1t, T1, n, 256);
    k_prop256b<<<(n + 3) / 4, 256, 0, stream>>>((const uint4*)T1, rowptr, es,
                                                dinv, b1, (uint4*)H, n);

    // ---- layer 2 ----
    dim3 g2((n + 127) / 128, 1);
    k_gemm_bf16<<<g2, 256, 0, stream>>>(H, W2t, T2, n, 128);
    k_prop128b<<<(n + 3) / 4, 256, 0, stream>>>((const uint4*)T2, rowptr, es,
                                                dinv, b2, out, n);
}

// Round 8
// 336.985 us; speedup vs baseline: 2.2464x; 1.1511x over previous
//
#include <hip/hip_runtime.h>

typedef short s16x8 __attribute__((ext_vector_type(8)));
typedef float f32x4 __attribute__((ext_vector_type(4)));
typedef float f32x2 __attribute__((ext_vector_type(2)));

#define TILE 2048  // edges per block in binning passes (256 thr x 8)

// ---------- bf16 helpers (bit-level, RNE) ----------
__device__ __forceinline__ unsigned int brne(float f) {
    unsigned int u = __float_as_uint(f);
    return (u + 0x7FFFu + ((u >> 16) & 1u)) >> 16;   // bf16 bits in low 16
}
__device__ __forceinline__ float blo(unsigned int u) { return __uint_as_float(u << 16); }
__device__ __forceinline__ float bhi(unsigned int u) { return __uint_as_float(u & 0xFFFF0000u); }

// accumulate 8 bf16 lanes of a uint4 row piece, scaled by wt
__device__ __forceinline__ void acc8(float* a, const uint4 u, const float wt) {
    a[0] += blo(u.x) * wt; a[1] += bhi(u.x) * wt;
    a[2] += blo(u.y) * wt; a[3] += bhi(u.y) * wt;
    a[4] += blo(u.z) * wt; a[5] += bhi(u.z) * wt;
    a[6] += blo(u.w) * wt; a[7] += bhi(u.w) * wt;
}

// ---------- fp8 e4m3 (OCP) helpers via HW cvt ----------
__device__ __forceinline__ unsigned int enc_fp8(float v) {
    return __builtin_amdgcn_cvt_pk_fp8_f32(v, v, 0, false) & 0xFF;
}
__device__ __forceinline__ void dec4(float* f, unsigned int u) {
    f32x2 lo = __builtin_amdgcn_cvt_pk_f32_fp8((int)u, false);
    f32x2 hi = __builtin_amdgcn_cvt_pk_f32_fp8((int)u, true);
    f[0] = lo[0]; f[1] = lo[1]; f[2] = hi[0]; f[3] = hi[1];
}
// accumulate 16 fp8 lanes of a uint4 row piece, scaled by wt
__device__ __forceinline__ void acc16(float* a, const uint4 u, const float wt) {
    float f[4];
    dec4(f, u.x); a[0] += f[0]*wt; a[1] += f[1]*wt; a[2]  += f[2]*wt; a[3]  += f[3]*wt;
    dec4(f, u.y); a[4] += f[0]*wt; a[5] += f[1]*wt; a[6]  += f[2]*wt; a[7]  += f[3]*wt;
    dec4(f, u.z); a[8] += f[0]*wt; a[9] += f[1]*wt; a[10] += f[2]*wt; a[11] += f[3]*wt;
    dec4(f, u.w); a[12]+= f[0]*wt; a[13]+= f[1]*wt; a[14] += f[2]*wt; a[15] += f[3]*wt;
}

// ---------------- binned CSR build ----------------
// bucket = dst >> 8 (256 nodes per bucket, nb = ceil(n/256) <= 256)

__global__ void k_bhist(const int* __restrict__ dst, int* __restrict__ bucket_cnt,
                        int e, int nb) {
    __shared__ int h[256];
    const int tid = threadIdx.x;
    h[tid] = 0;
    __syncthreads();
    const int base = blockIdx.x * TILE + tid;
#pragma unroll
    for (int k = 0; k < 8; k++) {
        const int i = base + k * 256;
        if (i < e) atomicAdd(&h[dst[i] >> 8], 1);
    }
    __syncthreads();
    if (tid < nb && h[tid]) atomicAdd(&bucket_cnt[tid], h[tid]);
}

__global__ void k_bscan(const int* __restrict__ bucket_cnt, int* __restrict__ bucket_base,
                        int* __restrict__ bucket_cursor, int nb, int e) {
    __shared__ int sh[256];
    const int tid = threadIdx.x;
    const int v = (tid < nb) ? bucket_cnt[tid] : 0;
    int x = v;
    sh[tid] = x;
    __syncthreads();
    for (int off = 1; off < 256; off <<= 1) {
        const int t = (tid >= off) ? sh[tid - off] : 0;
        __syncthreads();
        if (tid >= off) { x += t; sh[tid] = x; }
        __syncthreads();
    }
    if (tid < nb) { bucket_base[tid] = x - v; bucket_cursor[tid] = x - v; }
    if (tid == 0) bucket_base[nb] = e;
}

__global__ void k_bscatter(const int* __restrict__ src, const int* __restrict__ dst,
                           int* __restrict__ bucket_cursor, uint2* __restrict__ eb, int e) {
    __shared__ int h[256], hbase[256], h2[256];
    const int tid = threadIdx.x;
    h[tid] = 0; h2[tid] = 0;
    __syncthreads();
    const int base = blockIdx.x * TILE + tid;
    int s[8], d[8], b[8];
    bool val[8];
#pragma unroll
    for (int k = 0; k < 8; k++) {
        const int i = base + k * 256;
        val[k] = i < e;
        if (val[k]) {
            s[k] = src[i]; d[k] = dst[i]; b[k] = d[k] >> 8;
            atomicAdd(&h[b[k]], 1);
        }
    }
    __syncthreads();
    if (h[tid]) hbase[tid] = atomicAdd(&bucket_cursor[tid], h[tid]);
    __syncthreads();
#pragma unroll
    for (int k = 0; k < 8; k++) {
        if (val[k]) {
            const int off = atomicAdd(&h2[b[k]], 1);
            eb[hbase[b[k]] + off] = make_uint2((unsigned)s[k], (unsigned)d[k]);
        }
    }
}

__global__ void k_nhist(const uint2* __restrict__ eb, const int* __restrict__ bucket_base,
                        int* __restrict__ cnt, float* __restrict__ dinv, int n) {
    __shared__ int c[256];
    const int tid = threadIdx.x, b = blockIdx.x;
    c[tid] = 0;
    __syncthreads();
    const int beg = bucket_base[b], end = bucket_base[b + 1];
    for (int i = beg + tid; i < end; i += 256)
        atomicAdd(&c[eb[i].y & 255], 1);
    __syncthreads();
    const int node = b * 256 + tid;
    if (node < n) {
        cnt[node] = c[tid];
        dinv[node] = rsqrtf((float)(c[tid] + 1));  // deg includes self-loop
    }
}

__global__ void k_scan1(const int* __restrict__ cnt, int* __restrict__ rowptr,
                        int* __restrict__ part, int n) {
    __shared__ int sh[256];
    int tid = threadIdx.x;
    int i = blockIdx.x * 256 + tid;
    int v = (i < n) ? cnt[i] : 0;
    int x = v;
    sh[tid] = x;
    __syncthreads();
    for (int off = 1; off < 256; off <<= 1) {
        int t = (tid >= off) ? sh[tid - off] : 0;
        __syncthreads();
        if (tid >= off) { x += t; sh[tid] = x; }
        __syncthreads();
    }
    if (i < n) rowptr[i] = x - v;
    if (tid == 255) part[blockIdx.x] = x;
}

__global__ void k_scan2(int* __restrict__ part, int nb) {
    __shared__ int sh[256];
    int tid = threadIdx.x;
    int v = (tid < nb) ? part[tid] : 0;
    int x = v;
    sh[tid] = x;
    __syncthreads();
    for (int off = 1; off < 256; off <<= 1) {
        int t = (tid >= off) ? sh[tid - off] : 0;
        __syncthreads();
        if (tid >= off) { x += t; sh[tid] = x; }
        __syncthreads();
    }
    if (tid < nb) part[tid] = x - v;
}

__global__ void k_scan3(int* __restrict__ rowptr, const int* __restrict__ part,
                        int n, int e) {
    int i = blockIdx.x * blockDim.x + threadIdx.x;
    if (i < n) rowptr[i] = rowptr[i] + part[i >> 8];
    if (i == 0) rowptr[n] = e;
}

__global__ void k_place(const uint2* __restrict__ eb, const int* __restrict__ bucket_base,
                        const int* __restrict__ rowptr, int* __restrict__ es, int n) {
    __shared__ int offs[256];
    const int tid = threadIdx.x, b = blockIdx.x;
    offs[tid] = 0;
    __syncthreads();
    const int beg = bucket_base[b], end = bucket_base[b + 1];
    for (int i = beg + tid; i < end; i += 256) {
        const uint2 ed = eb[i];
        const int d = (int)ed.y;
        const int local = atomicAdd(&offs[d & 255], 1);
        es[rowptr[d] + local] = (int)ed.x;
    }
}

// ---------------- dtype prep ----------------
__global__ void k_cast_x(const float* __restrict__ x, unsigned int* __restrict__ xb2,
                         int total4) {
    int i = blockIdx.x * blockDim.x + threadIdx.x;
    if (i >= total4) return;
    float4 v = ((const float4*)x)[i];
    uint2 p;
    p.x = brne(v.x) | (brne(v.y) << 16);
    p.y = brne(v.z) | (brne(v.w) << 16);
    ((uint2*)xb2)[i] = p;
}

// W[K][N] fp32 -> Wt[N][K] bf16 (K=256, N = 1<<nshift)
__global__ void k_tW(const float* __restrict__ W, unsigned short* __restrict__ Wt,
                     int total, int nshift) {
    int t = blockIdx.x * blockDim.x + threadIdx.x;
    if (t >= total) return;
    int k = t >> nshift;
    int nn = t & ((1 << nshift) - 1);
    Wt[(size_t)nn * 256 + k] = (unsigned short)brne(W[t]);
}

// ---------------- bf16 MFMA GEMM: C[M,Nc] = A[M,256] @ Bt[Nc,256]^T ----------------
// FP8OUT: quantize output to fp8 e4m3 (T1); else bf16 (T2).
#define LP 40
template <bool FP8OUT>
__global__ __launch_bounds__(256) void k_gemm_bf16(const unsigned short* __restrict__ A,
                                                   const unsigned short* __restrict__ Bt,
                                                   void* __restrict__ Cout,
                                                   int M, int Nc) {
    __shared__ unsigned short As[128 * LP];
    __shared__ unsigned short Bs[128 * LP];

    const int tid = threadIdx.x;
    const int wave = tid >> 6, lane = tid & 63;
    const int wm = (wave >> 1) * 64, wn = (wave & 1) * 64;
    const int l15 = lane & 15, quad = lane >> 4;
    const int mBase = blockIdx.x * 128, nBase = blockIdx.y * 128;

    f32x4 acc[4][4];
#pragma unroll
    for (int i = 0; i < 4; i++)
#pragma unroll
        for (int j = 0; j < 4; j++) acc[i][j] = (f32x4){0.f, 0.f, 0.f, 0.f};

    const int c0 = tid, c1 = 256 + tid;
    const int r0 = c0 >> 2, kc0 = c0 & 3;
    const int r1 = c1 >> 2, kc1 = c1 & 3;
    int am0 = mBase + r0; if (am0 >= M) am0 = M - 1;
    int am1 = mBase + r1; if (am1 >= M) am1 = M - 1;
    const uint4* Ap0 = (const uint4*)A + (size_t)am0 * 32 + kc0;
    const uint4* Ap1 = (const uint4*)A + (size_t)am1 * 32 + kc1;
    const uint4* Bp0 = (const uint4*)Bt + (size_t)(nBase + r0) * 32 + kc0;
    const uint4* Bp1 = (const uint4*)Bt + (size_t)(nBase + r1) * 32 + kc1;

    for (int kt = 0; kt < 8; ++kt) {
        uint4 a0 = Ap0[kt * 4];
        uint4 a1 = Ap1[kt * 4];
        uint4 b0 = Bp0[kt * 4];
        uint4 b1 = Bp1[kt * 4];
        __syncthreads();
        *(uint4*)&As[r0 * LP + kc0 * 8] = a0;
        *(uint4*)&As[r1 * LP + kc1 * 8] = a1;
        *(uint4*)&Bs[r0 * LP + kc0 * 8] = b0;
        *(uint4*)&Bs[r1 * LP + kc1 * 8] = b1;
        __syncthreads();

        s16x8 af[4], bf[4];
#pragma unroll
        for (int i = 0; i < 4; i++)
            af[i] = *(const s16x8*)&As[(wm + i * 16 + l15) * LP + quad * 8];
#pragma unroll
        for (int j = 0; j < 4; j++)
            bf[j] = *(const s16x8*)&Bs[(wn + j * 16 + l15) * LP + quad * 8];
#pragma unroll
        for (int i = 0; i < 4; i++)
#pragma unroll
            for (int j = 0; j < 4; j++)
                acc[i][j] = __builtin_amdgcn_mfma_f32_16x16x32_bf16(af[i], bf[j], acc[i][j], 0, 0, 0);
    }

#pragma unroll
    for (int i = 0; i < 4; i++) {
        const int rowb = mBase + wm + i * 16 + quad * 4;
#pragma unroll
        for (int r = 0; r < 4; r++) {
            const int row = rowb + r;
            if (row < M) {
#pragma unroll
                for (int j = 0; j < 4; j++) {
                    const int col = nBase + wn + j * 16 + l15;
                    if (FP8OUT)
                        ((unsigned char*)Cout)[(size_t)row * Nc + col] =
                            (unsigned char)enc_fp8(acc[i][j][r]);
                    else
                        ((unsigned short*)Cout)[(size_t)row * Nc + col] =
                            (unsigned short)brne(acc[i][j][r]);
                }
            }
        }
    }
}

// ---------------- propagation ----------------
// L1: 256 feats fp8 = 16 uint4/row. Quarter-wave per edge -> 4 edges in
// flight; unroll 2 -> 8. shfl_xor(16,32) reduce; quad 0 stores H bf16.
__global__ void k_prop256f8(const uint4* __restrict__ X4,
                            const int* __restrict__ rowptr,
                            const int* __restrict__ es,
                            const float* __restrict__ dinv,
                            const float* __restrict__ bias,
                            uint4* __restrict__ Y4, int n) {
    const int wid = (int)((blockIdx.x * blockDim.x + threadIdx.x) >> 6);
    const int lane = threadIdx.x & 63;
    const int quad = lane >> 4, l16 = lane & 15;
    if (wid >= n) return;
    const float dd = dinv[wid];
    float a[16];
#pragma unroll
    for (int k = 0; k < 16; k++) a[k] = 0.f;
    {
        const uint4 v = X4[(size_t)wid * 16 + l16];
        if (quad == 0) acc16(a, v, dd * dd);
    }
    const int beg = rowptr[wid], end = rowptr[wid + 1];
    int j = beg + quad;
    for (; j + 4 < end; j += 8) {
        const int s0 = es[j], s1 = es[j + 4];
        const float w0 = dinv[s0] * dd, w1 = dinv[s1] * dd;
        const uint4 u0 = X4[(size_t)s0 * 16 + l16];
        const uint4 u1 = X4[(size_t)s1 * 16 + l16];
        acc16(a, u0, w0);
        acc16(a, u1, w1);
    }
    if (j < end) {
        const int s0 = es[j];
        const float w0 = dinv[s0] * dd;
        const uint4 u0 = X4[(size_t)s0 * 16 + l16];
        acc16(a, u0, w0);
    }
#pragma unroll
    for (int k = 0; k < 16; k++) {
        a[k] += __shfl_xor(a[k], 16);
        a[k] += __shfl_xor(a[k], 32);
    }
    if (quad == 0) {
        const float4* bp = (const float4*)bias + l16 * 4;
#pragma unroll
        for (int q = 0; q < 4; q++) {
            const float4 b = bp[q];
            a[q * 4 + 0] = fmaxf(a[q * 4 + 0] + b.x, 0.f);
            a[q * 4 + 1] = fmaxf(a[q * 4 + 1] + b.y, 0.f);
            a[q * 4 + 2] = fmaxf(a[q * 4 + 2] + b.z, 0.f);
            a[q * 4 + 3] = fmaxf(a[q * 4 + 3] + b.w, 0.f);
        }
        uint4 p0, p1;
        p0.x = brne(a[0])  | (brne(a[1])  << 16);
        p0.y = brne(a[2])  | (brne(a[3])  << 16);
        p0.z = brne(a[4])  | (brne(a[5])  << 16);
        p0.w = brne(a[6])  | (brne(a[7])  << 16);
        p1.x = brne(a[8])  | (brne(a[9])  << 16);
        p1.y = brne(a[10]) | (brne(a[11]) << 16);
        p1.z = brne(a[12]) | (brne(a[13]) << 16);
        p1.w = brne(a[14]) | (brne(a[15]) << 16);
        Y4[(size_t)wid * 32 + l16 * 2] = p0;
        Y4[(size_t)wid * 32 + l16 * 2 + 1] = p1;
    }
}

// L2: 128 feats bf16 = 16 uint4/row... wait: 128 bf16 = 256 B = 16 uint4.
// Quarter-wave (16 lanes x 16B) per edge -> 4 edges in flight; unroll 2 -> 8.
// shfl_xor(16,32) reduce; quad 0 stores fp32 (8 floats per lane).
__global__ void k_prop128b(const uint4* __restrict__ X4,
                           const int* __restrict__ rowptr,
                           const int* __restrict__ es,
                           const float* __restrict__ dinv,
                           const float* __restrict__ bias,
                           float* __restrict__ Yout, int n) {
    const int wid = (int)((blockIdx.x * blockDim.x + threadIdx.x) >> 6);
    const int lane = threadIdx.x & 63;
    const int quad = lane >> 4, l16 = lane & 15;
    if (wid >= n) return;
    const float dd = dinv[wid];
    float a[8];
#pragma unroll
    for (int k = 0; k < 8; k++) a[k] = 0.f;
    {
        const uint4 v = X4[(size_t)wid * 16 + l16];
        if (quad == 0) acc8(a, v, dd * dd);
    }
    const int beg = rowptr[wid], end = rowptr[wid + 1];
    int j = beg + quad;
    for (; j + 4 < end; j += 8) {
        const int s0 = es[j], s1 = es[j + 4];
        const float w0 = dinv[s0] * dd, w1 = dinv[s1] * dd;
        const uint4 u0 = X4[(size_t)s0 * 16 + l16];
        const uint4 u1 = X4[(size_t)s1 * 16 + l16];
        acc8(a, u0, w0);
        acc8(a, u1, w1);
    }
    if (j < end) {
        const int s0 = es[j];
        const float w0 = dinv[s0] * dd;
        const uint4 u0 = X4[(size_t)s0 * 16 + l16];
        acc8(a, u0, w0);
    }
#pragma unroll
    for (int k = 0; k < 8; k++) {
        a[k] += __shfl_xor(a[k], 16);
        a[k] += __shfl_xor(a[k], 32);
    }
    if (quad == 0) {
        // lane l16 owns feats [l16*8, l16*8+8)
        const float4 b0 = ((const float4*)bias)[l16 * 2];
        const float4 b1 = ((const float4*)bias)[l16 * 2 + 1];
        float4* op = (float4*)Yout + (size_t)wid * 32 + l16 * 2;
        op[0] = make_float4(a[0] + b0.x, a[1] + b0.y, a[2] + b0.z, a[3] + b0.w);
        op[1] = make_float4(a[4] + b1.x, a[5] + b1.y, a[6] + b1.z, a[7] + b1.w);
    }
}

extern "C" void kernel_launch(void* const* d_in, const int* in_sizes, int n_in,
                              void* d_out, int out_size, void* d_ws, size_t ws_size,
                              hipStream_t stream) {
    const float* x  = (const float*)d_in[0];
    const int*   ei = (const int*)d_in[1];
    const float* W1 = (const float*)d_in[2];
    const float* b1 = (const float*)d_in[3];
    const float* W2 = (const float*)d_in[4];
    const float* b2 = (const float*)d_in[5];
    float* out = (float*)d_out;

    const int n = in_sizes[0] / 256;  // 50000
    const int e = in_sizes[1] / 2;    // 1600000
    const int* src = ei;
    const int* dst = ei + e;
    const int nb = (n + 255) >> 8;    // 196 coarse buckets (<=256 required)

    char* wsp = (char*)d_ws;
    size_t off = 0;
    auto alloc = [&](size_t bytes) -> char* {
        char* p = wsp + off;
        off += (bytes + 511) & ~(size_t)511;
        return p;
    };
    int*   cnt     = (int*)alloc(sizeof(int) * n);
    float* dinv    = (float*)alloc(sizeof(float) * n);
    int*   rowptr  = (int*)alloc(sizeof(int) * (n + 1));
    int*   part    = (int*)alloc(sizeof(int) * 256);
    int*   bcnt    = (int*)alloc(sizeof(int) * 256);
    int*   bbase   = (int*)alloc(sizeof(int) * 257);
    int*   bcur    = (int*)alloc(sizeof(int) * 256);
    int*   es      = (int*)alloc(sizeof(int) * e);
    unsigned short* xb  = (unsigned short*)alloc(2ull * n * 256);   // bf16 x
    unsigned short* W1t = (unsigned short*)alloc(2ull * 256 * 256); // [N][K]
    unsigned short* W2t = (unsigned short*)alloc(2ull * 128 * 256); // [N][K]
    unsigned char*  T1  = (unsigned char*)alloc((size_t)n * 256);   // x@W1 fp8
    unsigned short* H   = (unsigned short*)alloc(2ull * n * 256);   // relu(prop+b1) bf16
    unsigned short* T2  = (unsigned short*)alloc(2ull * n * 128);   // H@W2 bf16
    // eb (coarse-binned (src,dst) pairs, 8B*e = 12.8MB) aliases H (25.6MB):
    // build finishes (k_place) before H is first written (prop256f8).
    uint2* eb = (uint2*)H;

    const int nb_n = (n + 255) / 256;
    const int nb_t = (e + TILE - 1) / TILE;

    // ---- binned CSR build ----
    (void)hipMemsetAsync(bcnt, 0, sizeof(int) * 256, stream);
    k_bhist<<<nb_t, 256, 0, stream>>>(dst, bcnt, e, nb);
    k_bscan<<<1, 256, 0, stream>>>(bcnt, bbase, bcur, nb, e);
    k_bscatter<<<nb_t, 256, 0, stream>>>(src, dst, bcur, eb, e);
    k_nhist<<<nb, 256, 0, stream>>>(eb, bbase, cnt, dinv, n);
    k_scan1<<<nb_n, 256, 0, stream>>>(cnt, rowptr, part, n);
    k_scan2<<<1, 256, 0, stream>>>(part, nb_n);
    k_scan3<<<nb_n, 256, 0, stream>>>(rowptr, part, n, e);
    k_place<<<nb, 256, 0, stream>>>(eb, bbase, rowptr, es, n);

    // ---- dtype prep ----
    const int total4 = n * 256 / 4;
    k_cast_x<<<(total4 + 255) / 256, 256, 0, stream>>>(x, (unsigned int*)xb, total4);
    k_tW<<<(256 * 256 + 255) / 256, 256, 0, stream>>>(W1, W1t, 256 * 256, 8);
    k_tW<<<(256 * 128 + 255) / 256, 256, 0, stream>>>(W2, W2t, 256 * 128, 7);

    // ---- layer 1: T1 = fp8(x@W1); H = bf16(relu(prop(T1)+b1)) ----
    dim3 g1((n + 127) / 128, 2);
    k_gemm_bf16<true><<<g1, 256, 0, stream>>>(xb, W1t, T1, n, 256);
    k_prop256f8<<<(n + 3) / 4, 256, 0, stream>>>((const uint4*)T1, rowptr, es,
                                                 dinv, b1, (uint4*)H, n);

    // ---- layer 2: T2 = bf16(H@W2); out = prop(T2)+b2 ----
    dim3 g2((n + 127) / 128, 1);
    k_gemm_bf16<false><<<g2, 256, 0, stream>>>(H, W2t, T2, n, 128);
    k_prop128b<<<(n + 3) / 4, 256, 0, stream>>>((const uint4*)T2, rowptr, es,
                                                dinv, b2, out, n);
}

// Round 9
// 317.662 us; speedup vs baseline: 2.3831x; 1.0608x over previous
//
#include <hip/hip_runtime.h>

typedef short s16x8 __attribute__((ext_vector_type(8)));
typedef float f32x4 __attribute__((ext_vector_type(4)));
typedef float f32x2 __attribute__((ext_vector_type(2)));

#define TILE 2048  // edges per block in binning passes (256 thr x 8)

// ---------- bf16 helpers (bit-level, RNE) ----------
__device__ __forceinline__ unsigned int brne(float f) {
    unsigned int u = __float_as_uint(f);
    return (u + 0x7FFFu + ((u >> 16) & 1u)) >> 16;   // bf16 bits in low 16
}
__device__ __forceinline__ float blo(unsigned int u) { return __uint_as_float(u << 16); }
__device__ __forceinline__ float bhi(unsigned int u) { return __uint_as_float(u & 0xFFFF0000u); }

// accumulate 8 bf16 lanes of a uint4 row piece, scaled by wt
__device__ __forceinline__ void acc8(float* a, const uint4 u, const float wt) {
    a[0] += blo(u.x) * wt; a[1] += bhi(u.x) * wt;
    a[2] += blo(u.y) * wt; a[3] += bhi(u.y) * wt;
    a[4] += blo(u.z) * wt; a[5] += bhi(u.z) * wt;
    a[6] += blo(u.w) * wt; a[7] += bhi(u.w) * wt;
}

// ---------- fp8 e4m3 (OCP) helpers via HW cvt ----------
__device__ __forceinline__ unsigned int enc_fp8(float v) {
    return __builtin_amdgcn_cvt_pk_fp8_f32(v, v, 0, false) & 0xFF;
}
// packed accumulate: 16 fp8 of a uint4 into 8 f32x2 accumulators (v_pk_fma path)
__device__ __forceinline__ void acc16p(f32x2* a, const uint4 u, const f32x2 w2) {
    a[0] += __builtin_amdgcn_cvt_pk_f32_fp8((int)u.x, false) * w2;
    a[1] += __builtin_amdgcn_cvt_pk_f32_fp8((int)u.x, true)  * w2;
    a[2] += __builtin_amdgcn_cvt_pk_f32_fp8((int)u.y, false) * w2;
    a[3] += __builtin_amdgcn_cvt_pk_f32_fp8((int)u.y, true)  * w2;
    a[4] += __builtin_amdgcn_cvt_pk_f32_fp8((int)u.z, false) * w2;
    a[5] += __builtin_amdgcn_cvt_pk_f32_fp8((int)u.z, true)  * w2;
    a[6] += __builtin_amdgcn_cvt_pk_f32_fp8((int)u.w, false) * w2;
    a[7] += __builtin_amdgcn_cvt_pk_f32_fp8((int)u.w, true)  * w2;
}

// ---------------- binned CSR build ----------------
// bucket = dst >> 8 (256 nodes per bucket); bucket b <-> nodes [b*256,b*256+255]

__global__ void k_bhist(const int* __restrict__ dst, int* __restrict__ bucket_cnt,
                        int e, int nb) {
    __shared__ int h[256];
    const int tid = threadIdx.x;
    h[tid] = 0;
    __syncthreads();
    const int base = blockIdx.x * TILE + tid;
#pragma unroll
    for (int k = 0; k < 8; k++) {
        const int i = base + k * 256;
        if (i < e) atomicAdd(&h[dst[i] >> 8], 1);
    }
    __syncthreads();
    if (tid < nb && h[tid]) atomicAdd(&bucket_cnt[tid], h[tid]);
}

__global__ void k_bscan(const int* __restrict__ bucket_cnt, int* __restrict__ bucket_base,
                        int* __restrict__ bucket_cursor, int nb, int e) {
    __shared__ int sh[256];
    const int tid = threadIdx.x;
    const int v = (tid < nb) ? bucket_cnt[tid] : 0;
    int x = v;
    sh[tid] = x;
    __syncthreads();
    for (int off = 1; off < 256; off <<= 1) {
        const int t = (tid >= off) ? sh[tid - off] : 0;
        __syncthreads();
        if (tid >= off) { x += t; sh[tid] = x; }
        __syncthreads();
    }
    if (tid < nb) { bucket_base[tid] = x - v; bucket_cursor[tid] = x - v; }
    if (tid == 0) bucket_base[nb] = e;
}

__global__ void k_bscatter(const int* __restrict__ src, const int* __restrict__ dst,
                           int* __restrict__ bucket_cursor, uint2* __restrict__ eb, int e) {
    __shared__ int h[256], hbase[256], h2[256];
    const int tid = threadIdx.x;
    h[tid] = 0; h2[tid] = 0;
    __syncthreads();
    const int base = blockIdx.x * TILE + tid;
    int s[8], d[8], b[8];
    bool val[8];
#pragma unroll
    for (int k = 0; k < 8; k++) {
        const int i = base + k * 256;
        val[k] = i < e;
        if (val[k]) {
            s[k] = src[i]; d[k] = dst[i]; b[k] = d[k] >> 8;
            atomicAdd(&h[b[k]], 1);
        }
    }
    __syncthreads();
    if (h[tid]) hbase[tid] = atomicAdd(&bucket_cursor[tid], h[tid]);
    __syncthreads();
#pragma unroll
    for (int k = 0; k < 8; k++) {
        if (val[k]) {
            const int off = atomicAdd(&h2[b[k]], 1);
            eb[hbase[b[k]] + off] = make_uint2((unsigned)s[k], (unsigned)d[k]);
        }
    }
}

// fused: per-bucket exact node histogram + dinv + block-local exclusive scan
// (rowptr holds LOCAL offsets after this; part[b] = bucket total)
__global__ void k_nhist_scan(const uint2* __restrict__ eb, const int* __restrict__ bucket_base,
                             int* __restrict__ rowptr, int* __restrict__ part,
                             float* __restrict__ dinv, int n) {
    __shared__ int c[256], sh[256];
    const int tid = threadIdx.x, b = blockIdx.x;
    c[tid] = 0;
    __syncthreads();
    const int beg = bucket_base[b], end = bucket_base[b + 1];
    for (int i = beg + tid; i < end; i += 256)
        atomicAdd(&c[eb[i].y & 255], 1);
    __syncthreads();
    const int v = c[tid];
    const int node = b * 256 + tid;
    if (node < n) dinv[node] = rsqrtf((float)(v + 1));  // deg includes self-loop
    int x = v;
    sh[tid] = x;
    __syncthreads();
    for (int off = 1; off < 256; off <<= 1) {
        const int t = (tid >= off) ? sh[tid - off] : 0;
        __syncthreads();
        if (tid >= off) { x += t; sh[tid] = x; }
        __syncthreads();
    }
    if (node <= n) rowptr[node] = x - v;       // local exclusive offset
    if (tid == 255) part[b] = x;               // bucket total
}

// fused: part-prefix (scan2) + rowptr globalization (scan3) + placement
__global__ void k_place(const uint2* __restrict__ eb, const int* __restrict__ bucket_base,
                        int* __restrict__ rowptr, const int* __restrict__ part,
                        int* __restrict__ es, int n, int nb) {
    __shared__ int sh[256], rp[256], offs[256];
    const int tid = threadIdx.x, b = blockIdx.x;
    // inclusive scan of part[] (196 entries)
    int x = (tid < nb) ? part[tid] : 0;
    sh[tid] = x;
    __syncthreads();
    for (int off = 1; off < 256; off <<= 1) {
        const int t = (tid >= off) ? sh[tid - off] : 0;
        __syncthreads();
        if (tid >= off) { x += t; sh[tid] = x; }
        __syncthreads();
    }
    const int prefix = (b > 0) ? sh[b - 1] : 0;
    const int node = b * 256 + tid;
    int rg = 0;
    if (node <= n) {
        rg = rowptr[node] + prefix;
        rowptr[node] = rg;                     // now global (props read this)
    }
    rp[tid] = rg;
    offs[tid] = 0;
    __syncthreads();
    const int beg = bucket_base[b], end = bucket_base[b + 1];
    for (int i = beg + tid; i < end; i += 256) {
        const uint2 ed = eb[i];
        const int d = (int)ed.y & 255;
        const int local = atomicAdd(&offs[d], 1);
        es[rp[d] + local] = (int)ed.x;
    }
}

// ---------------- dtype prep: both weight transposes in one kernel ----------------
// W1[K=256][256] -> W1t[256][256]; W2[K=256][128] -> W2t[128][256]
__global__ void k_tW2(const float* __restrict__ W1, const float* __restrict__ W2,
                      unsigned short* __restrict__ W1t, unsigned short* __restrict__ W2t) {
    const int t = blockIdx.x * 256 + threadIdx.x;
    if (t < 65536) {
        const int k = t >> 8, nn = t & 255;
        W1t[nn * 256 + k] = (unsigned short)brne(W1[t]);
    } else {
        const int u = t - 65536;
        const int k = u >> 7, nn = u & 127;
        W2t[nn * 256 + k] = (unsigned short)brne(W2[u]);
    }
}

// ---------------- MFMA GEMM: C[M,Nc] = A[M,256] @ Bt[Nc,256]^T ----------------
// AF32: A is fp32 (cast to bf16 in staging)   FP8OUT: C quantized to fp8 e4m3
#define LP 40
template <bool AF32, bool FP8OUT>
__global__ __launch_bounds__(256) void k_gemm(const void* __restrict__ Av,
                                              const unsigned short* __restrict__ Bt,
                                              void* __restrict__ Cout,
                                              int M, int Nc) {
    __shared__ unsigned short As[128 * LP];
    __shared__ unsigned short Bs[128 * LP];

    const int tid = threadIdx.x;
    const int wave = tid >> 6, lane = tid & 63;
    const int wm = (wave >> 1) * 64, wn = (wave & 1) * 64;
    const int l15 = lane & 15, quad = lane >> 4;
    const int mBase = blockIdx.x * 128, nBase = blockIdx.y * 128;

    f32x4 acc[4][4];
#pragma unroll
    for (int i = 0; i < 4; i++)
#pragma unroll
        for (int j = 0; j < 4; j++) acc[i][j] = (f32x4){0.f, 0.f, 0.f, 0.f};

    const int r0 = tid >> 2, kc0 = tid & 3;       // staged rows r0 and r0+64
    int am0 = mBase + r0;      if (am0 >= M) am0 = M - 1;
    int am1 = mBase + r0 + 64; if (am1 >= M) am1 = M - 1;

    const uint4* Ap0; const uint4* Ap1; const float4* Af0; const float4* Af1;
    if (AF32) {
        Af0 = (const float4*)Av + (size_t)am0 * 64 + kc0 * 2;
        Af1 = (const float4*)Av + (size_t)am1 * 64 + kc0 * 2;
    } else {
        Ap0 = (const uint4*)Av + (size_t)am0 * 32 + kc0;
        Ap1 = (const uint4*)Av + (size_t)am1 * 32 + kc0;
    }
    const uint4* Bp0 = (const uint4*)Bt + (size_t)(nBase + r0) * 32 + kc0;
    const uint4* Bp1 = (const uint4*)Bt + (size_t)(nBase + r0 + 64) * 32 + kc0;

    for (int kt = 0; kt < 8; ++kt) {
        uint4 a0, a1;
        if (AF32) {
            const float4 l0 = Af0[kt * 8], h0 = Af0[kt * 8 + 1];
            const float4 l1 = Af1[kt * 8], h1 = Af1[kt * 8 + 1];
            a0.x = brne(l0.x) | (brne(l0.y) << 16); a0.y = brne(l0.z) | (brne(l0.w) << 16);
            a0.z = brne(h0.x) | (brne(h0.y) << 16); a0.w = brne(h0.z) | (brne(h0.w) << 16);
            a1.x = brne(l1.x) | (brne(l1.y) << 16); a1.y = brne(l1.z) | (brne(l1.w) << 16);
            a1.z = brne(h1.x) | (brne(h1.y) << 16); a1.w = brne(h1.z) | (brne(h1.w) << 16);
        } else {
            a0 = Ap0[kt * 4];
            a1 = Ap1[kt * 4];
        }
        const uint4 b0 = Bp0[kt * 4];
        const uint4 b1 = Bp1[kt * 4];
        __syncthreads();
        *(uint4*)&As[r0 * LP + kc0 * 8] = a0;
        *(uint4*)&As[(r0 + 64) * LP + kc0 * 8] = a1;
        *(uint4*)&Bs[r0 * LP + kc0 * 8] = b0;
        *(uint4*)&Bs[(r0 + 64) * LP + kc0 * 8] = b1;
        __syncthreads();

        s16x8 af[4], bf[4];
#pragma unroll
        for (int i = 0; i < 4; i++)
            af[i] = *(const s16x8*)&As[(wm + i * 16 + l15) * LP + quad * 8];
#pragma unroll
        for (int j = 0; j < 4; j++)
            bf[j] = *(const s16x8*)&Bs[(wn + j * 16 + l15) * LP + quad * 8];
#pragma unroll
        for (int i = 0; i < 4; i++)
#pragma unroll
            for (int j = 0; j < 4; j++)
                acc[i][j] = __builtin_amdgcn_mfma_f32_16x16x32_bf16(af[i], bf[j], acc[i][j], 0, 0, 0);
    }

#pragma unroll
    for (int i = 0; i < 4; i++) {
        const int rowb = mBase + wm + i * 16 + quad * 4;
#pragma unroll
        for (int r = 0; r < 4; r++) {
            const int row = rowb + r;
            if (row < M) {
#pragma unroll
                for (int j = 0; j < 4; j++) {
                    const int col = nBase + wn + j * 16 + l15;
                    if (FP8OUT)
                        ((unsigned char*)Cout)[(size_t)row * Nc + col] =
                            (unsigned char)enc_fp8(acc[i][j][r]);
                    else
                        ((unsigned short*)Cout)[(size_t)row * Nc + col] =
                            (unsigned short)brne(acc[i][j][r]);
                }
            }
        }
    }
}

// ---------------- propagation ----------------
// L1: 256 feats fp8 = 16 uint4/row. Quarter-wave per edge -> 4 edges in
// flight; unroll 2 -> 8. Packed f32x2 accumulate (v_pk_fma). quad 0 stores H bf16.
__global__ void k_prop256f8(const uint4* __restrict__ X4,
                            const int* __restrict__ rowptr,
                            const int* __restrict__ es,
                            const float* __restrict__ dinv,
                            const float* __restrict__ bias,
                            uint4* __restrict__ Y4, int n) {
    const int wid = (int)((blockIdx.x * blockDim.x + threadIdx.x) >> 6);
    const int lane = threadIdx.x & 63;
    const int quad = lane >> 4, l16 = lane & 15;
    if (wid >= n) return;
    const float dd = dinv[wid];
    f32x2 a[8];
#pragma unroll
    for (int k = 0; k < 8; k++) a[k] = (f32x2){0.f, 0.f};
    {
        const uint4 v = X4[(size_t)wid * 16 + l16];
        if (quad == 0) acc16p(a, v, (f32x2){dd * dd, dd * dd});
    }
    const int beg = rowptr[wid], end = rowptr[wid + 1];
    int j = beg + quad;
    for (; j + 4 < end; j += 8) {
        const int s0 = es[j], s1 = es[j + 4];
        const float w0 = dinv[s0] * dd, w1 = dinv[s1] * dd;
        const uint4 u0 = X4[(size_t)s0 * 16 + l16];
        const uint4 u1 = X4[(size_t)s1 * 16 + l16];
        acc16p(a, u0, (f32x2){w0, w0});
        acc16p(a, u1, (f32x2){w1, w1});
    }
    if (j < end) {
        const int s0 = es[j];
        const float w0 = dinv[s0] * dd;
        const uint4 u0 = X4[(size_t)s0 * 16 + l16];
        acc16p(a, u0, (f32x2){w0, w0});
    }
#pragma unroll
    for (int k = 0; k < 8; k++) {
        a[k][0] += __shfl_xor(a[k][0], 16);
        a[k][1] += __shfl_xor(a[k][1], 16);
        a[k][0] += __shfl_xor(a[k][0], 32);
        a[k][1] += __shfl_xor(a[k][1], 32);
    }
    if (quad == 0) {
        // feats linear order: a[0].xy, a[1].xy, ..., a[7].xy at base l16*16
        const float4* bp = (const float4*)bias + l16 * 4;
#pragma unroll
        for (int q = 0; q < 4; q++) {
            const float4 b = bp[q];
            a[2 * q][0]     = fmaxf(a[2 * q][0] + b.x, 0.f);
            a[2 * q][1]     = fmaxf(a[2 * q][1] + b.y, 0.f);
            a[2 * q + 1][0] = fmaxf(a[2 * q + 1][0] + b.z, 0.f);
            a[2 * q + 1][1] = fmaxf(a[2 * q + 1][1] + b.w, 0.f);
        }
        uint4 p0, p1;
        p0.x = brne(a[0][0]) | (brne(a[0][1]) << 16);
        p0.y = brne(a[1][0]) | (brne(a[1][1]) << 16);
        p0.z = brne(a[2][0]) | (brne(a[2][1]) << 16);
        p0.w = brne(a[3][0]) | (brne(a[3][1]) << 16);
        p1.x = brne(a[4][0]) | (brne(a[4][1]) << 16);
        p1.y = brne(a[5][0]) | (brne(a[5][1]) << 16);
        p1.z = brne(a[6][0]) | (brne(a[6][1]) << 16);
        p1.w = brne(a[7][0]) | (brne(a[7][1]) << 16);
        Y4[(size_t)wid * 32 + l16 * 2] = p0;
        Y4[(size_t)wid * 32 + l16 * 2 + 1] = p1;
    }
}

// L2: 128 feats bf16 = 16 uint4/row. Quarter-wave per edge -> 4 edges in
// flight; unroll 2 -> 8. shfl_xor(16,32) reduce; quad 0 stores fp32.
__global__ void k_prop128b(const uint4* __restrict__ X4,
                           const int* __restrict__ rowptr,
                           const int* __restrict__ es,
                           const float* __restrict__ dinv,
                           const float* __restrict__ bias,
                           float* __restrict__ Yout, int n) {
    const int wid = (int)((blockIdx.x * blockDim.x + threadIdx.x) >> 6);
    const int lane = threadIdx.x & 63;
    const int quad = lane >> 4, l16 = lane & 15;
    if (wid >= n) return;
    const float dd = dinv[wid];
    float a[8];
#pragma unroll
    for (int k = 0; k < 8; k++) a[k] = 0.f;
    {
        const uint4 v = X4[(size_t)wid * 16 + l16];
        if (quad == 0) acc8(a, v, dd * dd);
    }
    const int beg = rowptr[wid], end = rowptr[wid + 1];
    int j = beg + quad;
    for (; j + 4 < end; j += 8) {
        const int s0 = es[j], s1 = es[j + 4];
        const float w0 = dinv[s0] * dd, w1 = dinv[s1] * dd;
        const uint4 u0 = X4[(size_t)s0 * 16 + l16];
        const uint4 u1 = X4[(size_t)s1 * 16 + l16];
        acc8(a, u0, w0);
        acc8(a, u1, w1);
    }
    if (j < end) {
        const int s0 = es[j];
        const float w0 = dinv[s0] * dd;
        const uint4 u0 = X4[(size_t)s0 * 16 + l16];
        acc8(a, u0, w0);
    }
#pragma unroll
    for (int k = 0; k < 8; k++) {
        a[k] += __shfl_xor(a[k], 16);
        a[k] += __shfl_xor(a[k], 32);
    }
    if (quad == 0) {
        const float4 b0 = ((const float4*)bias)[l16 * 2];
        const float4 b1 = ((const float4*)bias)[l16 * 2 + 1];
        float4* op = (float4*)Yout + (size_t)wid * 32 + l16 * 2;
        op[0] = make_float4(a[0] + b0.x, a[1] + b0.y, a[2] + b0.z, a[3] + b0.w);
        op[1] = make_float4(a[4] + b1.x, a[5] + b1.y, a[6] + b1.z, a[7] + b1.w);
    }
}

extern "C" void kernel_launch(void* const* d_in, const int* in_sizes, int n_in,
                              void* d_out, int out_size, void* d_ws, size_t ws_size,
                              hipStream_t stream) {
    const float* x  = (const float*)d_in[0];
    const int*   ei = (const int*)d_in[1];
    const float* W1 = (const float*)d_in[2];
    const float* b1 = (const float*)d_in[3];
    const float* W2 = (const float*)d_in[4];
    const float* b2 = (const float*)d_in[5];
    float* out = (float*)d_out;

    const int n = in_sizes[0] / 256;  // 50000
    const int e = in_sizes[1] / 2;    // 1600000
    const int* src = ei;
    const int* dst = ei + e;
    const int nb = (n + 255) >> 8;    // 196 buckets (<=256 required)

    char* wsp = (char*)d_ws;
    size_t off = 0;
    auto alloc = [&](size_t bytes) -> char* {
        char* p = wsp + off;
        off += (bytes + 511) & ~(size_t)511;
        return p;
    };
    float* dinv    = (float*)alloc(sizeof(float) * n);
    int*   rowptr  = (int*)alloc(sizeof(int) * (n + 1));
    int*   part    = (int*)alloc(sizeof(int) * 256);
    int*   bcnt    = (int*)alloc(sizeof(int) * 256);
    int*   bbase   = (int*)alloc(sizeof(int) * 257);
    int*   bcur    = (int*)alloc(sizeof(int) * 256);
    int*   es      = (int*)alloc(sizeof(int) * e);
    unsigned short* W1t = (unsigned short*)alloc(2ull * 256 * 256); // [N][K]
    unsigned short* W2t = (unsigned short*)alloc(2ull * 128 * 256); // [N][K]
    unsigned char*  T1  = (unsigned char*)alloc((size_t)n * 256);   // x@W1 fp8
    unsigned short* H   = (unsigned short*)alloc(2ull * n * 256);   // relu(prop+b1) bf16
    unsigned short* T2  = (unsigned short*)alloc(2ull * n * 128);   // H@W2 bf16
    // eb (binned (src,dst) pairs, 8B*e = 12.8MB) aliases H (25.6MB):
    // build finishes (k_place) before H is first written (prop256f8).
    uint2* eb = (uint2*)H;

    const int nb_t = (e + TILE - 1) / TILE;

    // ---- binned CSR build (6 dispatches) ----
    (void)hipMemsetAsync(bcnt, 0, sizeof(int) * 256, stream);
    k_bhist<<<nb_t, 256, 0, stream>>>(dst, bcnt, e, nb);
    k_bscan<<<1, 256, 0, stream>>>(bcnt, bbase, bcur, nb, e);
    k_bscatter<<<nb_t, 256, 0, stream>>>(src, dst, bcur, eb, e);
    k_nhist_scan<<<nb, 256, 0, stream>>>(eb, bbase, rowptr, part, dinv, n);
    k_place<<<nb, 256, 0, stream>>>(eb, bbase, rowptr, part, es, n, nb);

    // ---- weights ----
    k_tW2<<<(65536 + 32768) / 256, 256, 0, stream>>>(W1, W2, W1t, W2t);

    // ---- layer 1: T1 = fp8(x@W1)  (fp32 A cast fused in staging) ----
    dim3 g1((n + 127) / 128, 2);
    k_gemm<true, true><<<g1, 256, 0, stream>>>(x, W1t, T1, n, 256);
    k_prop256f8<<<(n + 3) / 4, 256, 0, stream>>>((const uint4*)T1, rowptr, es,
                                                 dinv, b1, (uint4*)H, n);

    // ---- layer 2: T2 = bf16(H@W2); out = prop(T2)+b2 ----
    dim3 g2((n + 127) / 128, 1);
    k_gemm<false, false><<<g2, 256, 0, stream>>>(H, W2t, T2, n, 128);
    k_prop128b<<<(n + 3) / 4, 256, 0, stream>>>((const uint4*)T2, rowptr, es,
                                                dinv, b2, out, n);
}